// Round 7
// baseline (463.690 us; speedup 1.0000x reference)
//
#include <hip/hip_runtime.h>

using u16 = unsigned short;
using f32x4 = __attribute__((ext_vector_type(4))) float;
using short8 = __attribute__((ext_vector_type(8))) short;

__device__ __forceinline__ float bf2f(u16 u) {
    union { unsigned int i; float f; } v; v.i = ((unsigned int)u) << 16; return v.f;
}
__device__ __forceinline__ u16 f2bf(float f) {
    union { float f; unsigned int i; } v; v.f = f;
    unsigned int u = v.i;
    u += 0x7fffu + ((u >> 16) & 1u);
    return (u16)(u >> 16);
}
__device__ __forceinline__ void gload16(const u16* g, u16* l) {
    __builtin_amdgcn_global_load_lds((const __attribute__((address_space(1))) void*)g,
                                     (__attribute__((address_space(3))) void*)l, 16, 0, 0);
}
#define WAITV0() asm volatile("s_waitcnt vmcnt(0)" ::: "memory")
__device__ __forceinline__ void barrier_() {
    asm volatile("" ::: "memory");
    __builtin_amdgcn_s_barrier();
    asm volatile("" ::: "memory");
}

// ---------------- fused prep: weight transposes + ssum + bias MLP ----------------
// winp [2816][512]: 32-row group = 16 val rows (jj=(n>>5)*16+(n&15)) then 16 gate rows (R5 layout)
__global__ __launch_bounds__(256) void prep_all(
    const float* __restrict__ Wq, const float* __restrict__ Wkv,
    const float* __restrict__ Wo, const float* __restrict__ Win,
    const float* __restrict__ Wout, const float* __restrict__ cg,
    const float* __restrict__ w1, const float* __restrict__ b1,
    const float* __restrict__ w2, const float* __restrict__ b2,
    const float* __restrict__ w3, const float* __restrict__ b3,
    u16* __restrict__ wqkvt, u16* __restrict__ wot,
    u16* __restrict__ winp, u16* __restrict__ woutt,
    float* __restrict__ ssum, float* __restrict__ bias)
{
    if (blockIdx.x < 12544) {
        int i = blockIdx.x * 256 + threadIdx.x;
        if (i < 1536 * 512) {
            int n = i >> 9, c = i & 511;
            float v = (n < 512) ? Wq[c * 512 + n] : Wkv[c * 1024 + (n - 512)];
            wqkvt[i] = f2bf(v); return;
        }
        i -= 1536 * 512;
        if (i < 512 * 512) {
            int cc = i >> 9, k = i & 511;
            wot[i] = f2bf(Wo[k * 512 + cc]); return;
        }
        i -= 512 * 512;
        if (i < 2816 * 512) {
            int n = i >> 9, c = i & 511;
            int jj = ((n >> 5) << 4) + (n & 15);
            int gate = (n >> 4) & 1;
            float v = (jj < 1365) ? Win[c * 2730 + jj + gate * 1365] : 0.f;
            winp[i] = f2bf(v); return;
        }
        i -= 2816 * 512;
        if (i < 512 * 1408) {
            int cc = i / 1408, j = i % 1408;
            float v = (j < 1365) ? Wout[j * 512 + cc] * cg[j] : 0.f;
            woutt[i] = f2bf(v); return;
        }
        return;
    }
    if (blockIdx.x < 12544 + 128) {
        int c = ((blockIdx.x - 12544) << 2) + (threadIdx.x >> 6);
        int lane = threadIdx.x & 63;
        float s = 0.f;
        for (int j = lane; j < 1365; j += 64) s += Wout[j * 512 + c] * cg[j];
        for (int off = 32; off; off >>= 1) s += __shfl_xor(s, off);
        if (lane == 0) ssum[c] = s;
        return;
    }
    {
        __shared__ float h1[256], h2[256];
        int rc = blockIdx.x - 12544 - 128;
        int ti = rc >> 4, tj = rc & 15;
        int j = threadIdx.x;
        float r = (float)(ti - tj);
        float rl = (r > 0.f) ? logf(r + 1.f) : ((r < 0.f) ? -logf(1.f - r) : 0.f);
        float a = rl * w1[j] + b1[j];
        h1[j] = a / (1.f + __expf(-a));
        __syncthreads();
        float acc = b2[j];
        for (int k = 0; k < 256; ++k) acc += h1[k] * w2[k * 256 + j];
        h2[j] = acc / (1.f + __expf(-acc));
        __syncthreads();
        if (j < 8) {
            float ab = b3[j];
            for (int k = 0; k < 256; ++k) ab += h2[k] * w3[k * 8 + j];
            bias[j * 256 + ti * 16 + tj] = ab;
        }
    }
}

// ---------------- K1: temporal LayerNorm, write xn & xt token-major bf16 ----------------
__global__ __launch_bounds__(256) void k1_norm(
    const float* __restrict__ x, const int* __restrict__ frp,
    const float* __restrict__ g_norm, const float* __restrict__ pos_emb,
    const float* __restrict__ fr_emb,
    u16* __restrict__ xn, u16* __restrict__ xt)
{
    __shared__ u16 tile[256 * 34];
    const int bid = blockIdx.x;
    const int b = bid >> 10, rem = bid & 1023;
    const int hw0 = (rem >> 4) << 4;
    const int c0 = (rem & 15) << 5;
    const int tid = threadIdx.x;
    const int hwl = tid & 15, cl = tid >> 4;
    const int fr = frp[0] - 1;
    float v[2][16], mean2[2], ri2[2], gg2[2], fv2[2];
    for (int cp = 0; cp < 2; ++cp) {
        const int c = c0 + cl + (cp << 4);
        const float* xp = x + (size_t)(b * 512 + c) * 16384 + hw0 + hwl;
        const float fv = fr_emb[fr * 512 + c];
        float s1 = 0.f, s2 = 0.f;
#pragma unroll
        for (int t = 0; t < 16; ++t) {
            float xv = xp[t * 1024];
            v[cp][t] = xv;
            float xe = xv + pos_emb[t * 512 + c] + fv;
            s1 += xe; s2 += xe * xe;
        }
        float m = s1 * 0.0625f;
        float var = s2 * 0.0625f - m * m;
        mean2[cp] = m; ri2[cp] = rsqrtf(fmaxf(var, 1e-5f));
        gg2[cp] = g_norm[c]; fv2[cp] = fv;
    }
    for (int cp = 0; cp < 2; ++cp) {
        const int c = c0 + cl + (cp << 4);
#pragma unroll
        for (int t = 0; t < 16; ++t) {
            float xe = v[cp][t] + pos_emb[t * 512 + c] + fv2[cp];
            tile[((t << 4) + hwl) * 34 + cl + (cp << 4)] = f2bf((xe - mean2[cp]) * ri2[cp] * gg2[cp]);
        }
    }
    __syncthreads();
    for (int it = 0; it < 32; ++it) {
        int rowl = (tid >> 5) + (it << 3);
        int col = tid & 31;
        size_t p = (size_t)b * 16384 + (size_t)(rowl >> 4) * 1024 + hw0 + (rowl & 15);
        xn[p * 512 + c0 + col] = tile[rowl * 34 + col];
    }
    __syncthreads();
    for (int cp = 0; cp < 2; ++cp)
#pragma unroll
        for (int t = 0; t < 16; ++t)
            tile[((t << 4) + hwl) * 34 + cl + (cp << 4)] = f2bf(v[cp][t]);
    __syncthreads();
    for (int it = 0; it < 32; ++it) {
        int rowl = (tid >> 5) + (it << 3);
        int col = tid & 31;
        size_t p = (size_t)b * 16384 + (size_t)(rowl >> 4) * 1024 + hw0 + (rowl & 15);
        xt[p * 512 + c0 + col] = tile[rowl * 34 + col];
    }
}

// ---------------- 2-barrier 128x128 GEMM (proven R5 structure; EPI 0,1,3) ----------------
template<int EPI>
__global__ __launch_bounds__(256, 2) void gemm_bt(
    const u16* __restrict__ A, const u16* __restrict__ B, int K, int Nb,
    u16* __restrict__ outb, float* __restrict__ outf,
    const u16* __restrict__ addb,
    const float* __restrict__ ssum, int ldOut)
{
    __shared__ u16 lds[2 * 128 * 64];
    __shared__ float smr[256];          // EPI3: [0:128) mean, [128:256) rinv
    u16* lA = lds;
    u16* lB = lds + 128 * 64;
    const int tid = threadIdx.x, lane = tid & 63, w = tid >> 6;
    const int wr = w >> 1, wc = w & 1;
    const int cpx = gridDim.x >> 3;
    const int wgid = (blockIdx.x & 7) * cpx + (blockIdx.x >> 3);
    const int p0 = (wgid / Nb) * 128, n0 = (wgid % Nb) * 128;
    f32x4 acc[4][4] = {};
    float sst[4] = {}, sq[4] = {};
    for (int kt = 0; kt < K; kt += 64) {
        for (int i = 0; i < 4; ++i) {
            int rb = w * 4 + i;
            int r = rb * 8 + (lane >> 3);
            int cg = (lane & 7) ^ (r & 7);
            gload16(A + (size_t)(p0 + r) * K + (kt + cg * 8), lA + rb * 512);
            gload16(B + (size_t)(n0 + r) * K + (kt + cg * 8), lB + rb * 512);
        }
        __syncthreads();
#pragma unroll
        for (int kk = 0; kk < 2; ++kk) {
            short8 av[4], bv[4];
#pragma unroll
            for (int m = 0; m < 4; ++m) {
                int r = wr * 64 + m * 16 + (lane & 15);
                int cc = ((kk << 2) + (lane >> 4)) ^ (r & 7);
                av[m] = *(const short8*)(lA + r * 64 + cc * 8);
            }
#pragma unroll
            for (int n = 0; n < 4; ++n) {
                int r = wc * 64 + n * 16 + (lane & 15);
                int cc = ((kk << 2) + (lane >> 4)) ^ (r & 7);
                bv[n] = *(const short8*)(lB + r * 64 + cc * 8);
            }
            if constexpr (EPI == 3) {
                if (wc == 0) {
#pragma unroll
                    for (int m = 0; m < 4; ++m)
#pragma unroll
                        for (int j = 0; j < 8; ++j) {
                            float v = bf2f((u16)av[m][j]);
                            sst[m] += v; sq[m] += v * v;
                        }
                }
            }
#pragma unroll
            for (int m = 0; m < 4; ++m)
#pragma unroll
                for (int n = 0; n < 4; ++n)
                    acc[m][n] = __builtin_amdgcn_mfma_f32_16x16x32_bf16(av[m], bv[n], acc[m][n], 0, 0, 0);
        }
        __syncthreads();
    }

    if constexpr (EPI == 0 || EPI == 1) {
#pragma unroll
        for (int m = 0; m < 4; ++m)
#pragma unroll
            for (int n = 0; n < 4; ++n) {
                int row = p0 + wr * 64 + m * 16 + ((lane >> 4) << 2);
                int col = n0 + wc * 64 + n * 16 + (lane & 15);
#pragma unroll
                for (int r = 0; r < 4; ++r) {
                    float vv = acc[m][n][r];
                    if constexpr (EPI == 1) vv += bf2f(addb[(size_t)(row + r) * ldOut + col]);
                    outb[(size_t)(row + r) * ldOut + col] = f2bf(vv);
                }
            }
    } else {
        // EPI 3: finish inline stats, then channel-LN apply + residual + transposed fp32 store
        if (wc == 0) {
#pragma unroll
            for (int m = 0; m < 4; ++m) {
                float s = sst[m], q = sq[m];
                s += __shfl_xor(s, 16); q += __shfl_xor(q, 16);
                s += __shfl_xor(s, 32); q += __shfl_xor(q, 32);
                if ((lane >> 4) == 0) {
                    int row = wr * 64 + m * 16 + (lane & 15);
                    smr[row] = s; smr[128 + row] = q;
                }
            }
        }
        __syncthreads();
        if (tid < 128) {
            float mm = smr[tid] * (1.f / 1365.f);
            float var = smr[128 + tid] * (1.f / 1365.f) - mm * mm;
            smr[tid] = mm;
            smr[128 + tid] = rsqrtf(fmaxf(var, 1e-5f));
        }
        float* ldsT = (float*)lds;
        const int bb = p0 >> 14, tt = (p0 >> 10) & 15, hwb = p0 & 1023;
        float* outp = outf + (size_t)bb * 8388608 + (size_t)tt * 1024 + hwb;
        for (int cg4 = 0; cg4 < 4; ++cg4) {
            __syncthreads();
            if (wc == (cg4 >> 1)) {
#pragma unroll
                for (int m = 0; m < 4; ++m)
#pragma unroll
                    for (int nn = 0; nn < 2; ++nn) {
                        int n = ((cg4 & 1) << 1) + nn;
                        int cl2 = (nn << 4) + (lane & 15);
                        int col = n0 + wc * 64 + n * 16 + (lane & 15);
                        int rl = wr * 64 + m * 16 + ((lane >> 4) << 2);
                        float ssv = ssum[col];
#pragma unroll
                        for (int r = 0; r < 4; ++r) {
                            int p = p0 + rl + r;
                            float vv = smr[128 + rl + r] * (acc[m][n][r] - smr[rl + r] * ssv)
                                     + bf2f(addb[(size_t)p * 512 + col]);
                            ldsT[cl2 * 132 + rl + r] = vv;
                        }
                    }
            }
            __syncthreads();
#pragma unroll
            for (int e = 0; e < 16; ++e) {
                int li = e * 256 + tid;
                int cl2 = li >> 7, hwl = li & 127;
                outp[(size_t)(n0 + cg4 * 32 + cl2) * 16384 + hwl] = ldsT[cl2 * 132 + hwl];
            }
        }
    }
}

// ---------------- EXPERIMENT: stage-early double-buffered GEMM (EPI2 / GLU) ----------------
// T3-minimum recipe: prologue stage tile0; per tile: {vmcnt(0); barrier; issue next-tile
// staging into other buffer; ds_read+MFMA current}. ONE barrier per K-tile; staging HBM
// latency hides under current tile's compute. 64 KB LDS -> 2 blocks/CU.
__global__ __launch_bounds__(256, 2) void gemm_db_glu(
    const u16* __restrict__ A, const u16* __restrict__ B, int K, int Nb,
    u16* __restrict__ outb)
{
    __shared__ u16 lds[2][16384];     // per buf: A 128x64 | B 128x64
    const int tid = threadIdx.x, lane = tid & 63, w = tid >> 6;
    const int wr = w >> 1, wc = w & 1;
    const int cpx = gridDim.x >> 3;
    const int wgid = (blockIdx.x & 7) * cpx + (blockIdx.x >> 3);
    const int p0 = (wgid / Nb) * 128, n0 = (wgid % Nb) * 128;

    auto stage = [&](int buf, int kt) {
        u16* lA = lds[buf];
        u16* lB = lds[buf] + 8192;
        for (int i = 0; i < 4; ++i) {
            int rb = w * 4 + i;
            int r = rb * 8 + (lane >> 3);
            int cg = (lane & 7) ^ (r & 7);
            gload16(A + (size_t)(p0 + r) * K + (kt + cg * 8), lA + rb * 512);
            gload16(B + (size_t)(n0 + r) * K + (kt + cg * 8), lB + rb * 512);
        }
    };

    f32x4 acc[4][4] = {};
    stage(0, 0);
    const int NT = K >> 6;
    for (int i = 0; i < NT; ++i) {
        WAITV0();                 // own staging loads for tile i done
        barrier_();               // => all waves' loads done; prev-tile reads all consumed
        if (i + 1 < NT) stage((i + 1) & 1, (i + 1) << 6);
        const u16* lA = lds[i & 1];
        const u16* lB = lds[i & 1] + 8192;
#pragma unroll
        for (int kk = 0; kk < 2; ++kk) {
            short8 av[4], bv[4];
#pragma unroll
            for (int m = 0; m < 4; ++m) {
                int r = wr * 64 + m * 16 + (lane & 15);
                int cc = ((kk << 2) + (lane >> 4)) ^ (r & 7);
                av[m] = *(const short8*)(lA + r * 64 + cc * 8);
            }
#pragma unroll
            for (int n = 0; n < 4; ++n) {
                int r = wc * 64 + n * 16 + (lane & 15);
                int cc = ((kk << 2) + (lane >> 4)) ^ (r & 7);
                bv[n] = *(const short8*)(lB + r * 64 + cc * 8);
            }
#pragma unroll
            for (int m = 0; m < 4; ++m)
#pragma unroll
                for (int n = 0; n < 4; ++n)
                    acc[m][n] = __builtin_amdgcn_mfma_f32_16x16x32_bf16(av[m], bv[n], acc[m][n], 0, 0, 0);
        }
    }

    // GLU epilogue + time-shifted store (identical math to R5 EPI2)
#pragma unroll
    for (int m = 0; m < 4; ++m)
#pragma unroll
        for (int np = 0; np < 2; ++np) {
            int nv = np << 1;
            int colBase = n0 + wc * 64 + nv * 16 + (lane & 15);
            int jj = ((colBase >> 5) << 4) + (colBase & 15);
            int rowb = p0 + wr * 64 + m * 16 + ((lane >> 4) << 2);
            int t = (rowb >> 10) & 15;
#pragma unroll
            for (int r = 0; r < 4; ++r) {
                int p = rowb + r;
                float vv = acc[m][nv][r], gv = acc[m][nv + 1][r];
                float glu = vv * 0.5f * gv * (1.f + erff(gv * 0.70710678f));
                if (jj >= 1365) {
                    outb[(size_t)p * 1408 + jj] = 0;
                } else if (jj >= 683) {
                    if (t < 15) outb[(size_t)(p + 1024) * 1408 + jj] = f2bf(glu);
                    if (t == 0) outb[(size_t)p * 1408 + jj] = 0;
                } else {
                    outb[(size_t)p * 1408 + jj] = f2bf(glu);
                }
            }
        }
}

// ---------------- attention: per (8-pixel chunk, head) block; 2 blocks/CU ----------------
__global__ __launch_bounds__(256, 2) void attn_kernel(
    const u16* __restrict__ qkv, const float* __restrict__ bias, u16* __restrict__ o)
{
    __shared__ u16 qkvt[3 * 128 * 64];
    __shared__ float pl[128 * 17];
    __shared__ float bl[256];
    const int tid = threadIdx.x, lane = tid & 63, w = tid >> 6;
    const int pc = blockIdx.x, h = blockIdx.y;
    const int b = pc >> 7, hw0 = (pc & 127) << 3;
    bl[tid] = bias[h * 256 + tid];
    for (int i = 0; i < 12; ++i) {
        int idx = w * 12 + i;
        int s = idx >> 4, rb = idx & 15;
        int r = (rb << 3) + (lane >> 3);
        int cg = (lane & 7) ^ (r & 7);
        size_t grow = (size_t)b * 16384 + (size_t)(r >> 3) * 1024 + hw0 + (r & 7);
        gload16(qkv + grow * 1536 + s * 512 + h * 64 + cg * 8, qkvt + s * 8192 + rb * 512);
    }
    __syncthreads();
    {
        const int qrow = tid & 127, hh = tid >> 7;
        const int pix = qrow & 7, ti = qrow >> 3;
        float qv[64];
        const u16* qr = qkvt + qrow * 64;
#pragma unroll
        for (int cc = 0; cc < 8; ++cc) {
            short8 qq = *(const short8*)(qr + ((cc ^ (qrow & 7)) << 3));
#pragma unroll
            for (int j = 0; j < 8; ++j) qv[cc * 8 + j] = bf2f((u16)qq[j]);
        }
#pragma unroll
        for (int tj8 = 0; tj8 < 8; ++tj8) {
            int tj = (hh << 3) + tj8;
            int rk = (tj << 3) + pix;
            const u16* kr = qkvt + 8192 + rk * 64;
            float a = 0.f;
#pragma unroll
            for (int cc = 0; cc < 8; ++cc) {
                short8 kk = *(const short8*)(kr + ((cc ^ (rk & 7)) << 3));
#pragma unroll
                for (int j = 0; j < 8; ++j) a += qv[cc * 8 + j] * bf2f((u16)kk[j]);
            }
            pl[qrow * 17 + tj] = a * 0.125f + bl[(ti << 4) + tj];
        }
    }
    __syncthreads();
    if (tid < 128) {
        float sc[16];
#pragma unroll
        for (int j = 0; j < 16; ++j) sc[j] = pl[tid * 17 + j];
        float mx = sc[0];
#pragma unroll
        for (int j = 1; j < 16; ++j) mx = fmaxf(mx, sc[j]);
        float sum = 0.f;
#pragma unroll
        for (int j = 0; j < 16; ++j) { sc[j] = __expf(sc[j] - mx); sum += sc[j]; }
        float inv = 1.f / sum;
#pragma unroll
        for (int j = 0; j < 16; ++j) pl[tid * 17 + j] = sc[j] * inv;
    }
    __syncthreads();
    {
        const int pix = tid >> 5, dg = tid & 31;
        float v0[16], v1[16];
#pragma unroll
        for (int tj = 0; tj < 16; ++tj) {
            int rv = (tj << 3) + pix;
            unsigned int d = *(const unsigned int*)(qkvt + 16384 + rv * 64 +
                               (((dg >> 2) ^ (rv & 7)) << 3) + ((dg & 3) << 1));
            v0[tj] = bf2f((u16)(d & 0xffff));
            v1[tj] = bf2f((u16)(d >> 16));
        }
#pragma unroll
        for (int ti = 0; ti < 16; ++ti) {
            float a0 = 0.f, a1 = 0.f;
            const float* pr = pl + ((ti << 3) + pix) * 17;
#pragma unroll
            for (int tj = 0; tj < 16; ++tj) {
                float pv = pr[tj];
                a0 += pv * v0[tj];
                a1 += pv * v1[tj];
            }
            size_t p = (size_t)b * 16384 + (size_t)ti * 1024 + hw0 + pix;
            unsigned int pk = (unsigned int)f2bf(a0) | ((unsigned int)f2bf(a1) << 16);
            *(unsigned int*)(o + p * 512 + h * 64 + (dg << 1)) = pk;
        }
    }
}

extern "C" void kernel_launch(void* const* d_in, const int* in_sizes, int n_in,
                              void* d_out, int out_size, void* d_ws, size_t ws_size,
                              hipStream_t stream)
{
    const float* x       = (const float*)d_in[0];
    const int*   frp     = (const int*)d_in[1];
    const float* g_norm  = (const float*)d_in[2];
    const float* Wq      = (const float*)d_in[3];
    const float* Wkv     = (const float*)d_in[4];
    const float* Wo      = (const float*)d_in[5];
    const float* pos_emb = (const float*)d_in[6];
    const float* fr_emb  = (const float*)d_in[7];
    const float* w1      = (const float*)d_in[8];
    const float* b1      = (const float*)d_in[9];
    const float* w2      = (const float*)d_in[10];
    const float* b2      = (const float*)d_in[11];
    const float* w3      = (const float*)d_in[12];
    const float* b3      = (const float*)d_in[13];
    const float* Win     = (const float*)d_in[14];
    const float* chan_g  = (const float*)d_in[15];
    const float* Wout    = (const float*)d_in[16];

    char* ws = (char*)d_ws;
    u16*   wqkvt = (u16*)(ws + 0);
    u16*   wot   = (u16*)(ws + 1572864);
    u16*   winp  = (u16*)(ws + 2097152);
    u16*   woutt = (u16*)(ws + 4980736);
    float* ssum  = (float*)(ws + 6422528);
    float* biasb = (float*)(ws + 6424576);
    u16*   qkv   = (u16*)(ws + 8388608);     // reused as yg after attention
    u16*   xn    = (u16*)(ws + 109051904);   // reused as o_att after qkv GEMM
    u16*   xt    = (u16*)(ws + 142606336);
    u16*   x2    = (u16*)(ws + 176160768);
    u16*   o_att = xn;
    u16*   yg    = qkv;

    prep_all<<<12544 + 128 + 256, 256, 0, stream>>>(
        Wq, Wkv, Wo, Win, Wout, chan_g, w1, b1, w2, b2, w3, b3,
        wqkvt, wot, winp, woutt, ssum, biasb);
    k1_norm<<<2048, 256, 0, stream>>>(x, frp, g_norm, pos_emb, fr_emb, xn, xt);
    gemm_bt<0><<<256 * 12, 256, 0, stream>>>(xn, wqkvt, 512, 12, qkv, nullptr, nullptr,
                                             nullptr, 1536);
    attn_kernel<<<dim3(256, 8), 256, 0, stream>>>(qkv, biasb, o_att);
    gemm_bt<1><<<256 * 4, 256, 0, stream>>>(o_att, wot, 512, 4, x2, nullptr, xt,
                                            nullptr, 512);
    gemm_db_glu<<<256 * 22, 256, 0, stream>>>(x2, winp, 512, 22, yg);
    gemm_bt<3><<<256 * 4, 256, 0, stream>>>(yg, woutt, 1408, 4, nullptr, (float*)d_out, x2,
                                            ssum, 512);
}

// Round 8
// 416.812 us; speedup vs baseline: 1.1125x; 1.1125x over previous
//
#include <hip/hip_runtime.h>

using u16 = unsigned short;
using f32x4 = __attribute__((ext_vector_type(4))) float;
using short8 = __attribute__((ext_vector_type(8))) short;

__device__ __forceinline__ float bf2f(u16 u) {
    union { unsigned int i; float f; } v; v.i = ((unsigned int)u) << 16; return v.f;
}
__device__ __forceinline__ u16 f2bf(float f) {
    union { float f; unsigned int i; } v; v.f = f;
    unsigned int u = v.i;
    u += 0x7fffu + ((u >> 16) & 1u);
    return (u16)(u >> 16);
}
__device__ __forceinline__ void gload16(const u16* g, u16* l) {
    __builtin_amdgcn_global_load_lds((const __attribute__((address_space(1))) void*)g,
                                     (__attribute__((address_space(3))) void*)l, 16, 0, 0);
}

// ---------------- fused prologue: k1 temporal-LN + weight prep + ssum + bias MLP ----------------
// blocks [0,2048): k1_norm; [2048,14592): weight transposes; [14592,14720): ssum; [14720,14976): bias
__global__ __launch_bounds__(256) void prologue_all(
    const float* __restrict__ x, const int* __restrict__ frp,
    const float* __restrict__ g_norm, const float* __restrict__ pos_emb,
    const float* __restrict__ fr_emb,
    const float* __restrict__ Wq, const float* __restrict__ Wkv,
    const float* __restrict__ Wo, const float* __restrict__ Win,
    const float* __restrict__ Wout, const float* __restrict__ cg,
    const float* __restrict__ w1, const float* __restrict__ b1,
    const float* __restrict__ w2, const float* __restrict__ b2,
    const float* __restrict__ w3, const float* __restrict__ b3,
    u16* __restrict__ xn, u16* __restrict__ xt,
    u16* __restrict__ wqkvt, u16* __restrict__ wot,
    u16* __restrict__ winp, u16* __restrict__ woutt,
    float* __restrict__ ssum, float* __restrict__ bias)
{
    __shared__ u16 tile[256 * 34];
    __shared__ float h1[256], h2[256];
    const int bid = blockIdx.x;
    const int tid = threadIdx.x;
    if (bid < 2048) {
        // ---- k1: temporal LayerNorm, write xn & xt token-major bf16 ----
        const int b = bid >> 10, rem = bid & 1023;
        const int hw0 = (rem >> 4) << 4;
        const int c0 = (rem & 15) << 5;
        const int hwl = tid & 15, cl = tid >> 4;
        const int fr = frp[0] - 1;
        float v[2][16], mean2[2], ri2[2], gg2[2], fv2[2];
        for (int cp = 0; cp < 2; ++cp) {
            const int c = c0 + cl + (cp << 4);
            const float* xp = x + (size_t)(b * 512 + c) * 16384 + hw0 + hwl;
            const float fv = fr_emb[fr * 512 + c];
            float s1 = 0.f, s2 = 0.f;
#pragma unroll
            for (int t = 0; t < 16; ++t) {
                float xv = xp[t * 1024];
                v[cp][t] = xv;
                float xe = xv + pos_emb[t * 512 + c] + fv;
                s1 += xe; s2 += xe * xe;
            }
            float m = s1 * 0.0625f;
            float var = s2 * 0.0625f - m * m;
            mean2[cp] = m; ri2[cp] = rsqrtf(fmaxf(var, 1e-5f));
            gg2[cp] = g_norm[c]; fv2[cp] = fv;
        }
        for (int cp = 0; cp < 2; ++cp) {
            const int c = c0 + cl + (cp << 4);
#pragma unroll
            for (int t = 0; t < 16; ++t) {
                float xe = v[cp][t] + pos_emb[t * 512 + c] + fv2[cp];
                tile[((t << 4) + hwl) * 34 + cl + (cp << 4)] = f2bf((xe - mean2[cp]) * ri2[cp] * gg2[cp]);
            }
        }
        __syncthreads();
        for (int it = 0; it < 32; ++it) {
            int rowl = (tid >> 5) + (it << 3);
            int col = tid & 31;
            size_t p = (size_t)b * 16384 + (size_t)(rowl >> 4) * 1024 + hw0 + (rowl & 15);
            xn[p * 512 + c0 + col] = tile[rowl * 34 + col];
        }
        __syncthreads();
        for (int cp = 0; cp < 2; ++cp)
#pragma unroll
            for (int t = 0; t < 16; ++t)
                tile[((t << 4) + hwl) * 34 + cl + (cp << 4)] = f2bf(v[cp][t]);
        __syncthreads();
        for (int it = 0; it < 32; ++it) {
            int rowl = (tid >> 5) + (it << 3);
            int col = tid & 31;
            size_t p = (size_t)b * 16384 + (size_t)(rowl >> 4) * 1024 + hw0 + (rowl & 15);
            xt[p * 512 + c0 + col] = tile[rowl * 34 + col];
        }
        return;
    }
    if (bid < 14592) {
        int i = (bid - 2048) * 256 + tid;
        if (i < 1536 * 512) {
            int n = i >> 9, c = i & 511;
            float v = (n < 512) ? Wq[c * 512 + n] : Wkv[c * 1024 + (n - 512)];
            wqkvt[i] = f2bf(v); return;
        }
        i -= 1536 * 512;
        if (i < 512 * 512) {
            int cc = i >> 9, k = i & 511;
            wot[i] = f2bf(Wo[k * 512 + cc]); return;
        }
        i -= 512 * 512;
        if (i < 2816 * 512) {
            int n = i >> 9, c = i & 511;
            int jj = ((n >> 5) << 4) + (n & 15);
            int gate = (n >> 4) & 1;
            float v = (jj < 1365) ? Win[c * 2730 + jj + gate * 1365] : 0.f;
            winp[i] = f2bf(v); return;
        }
        i -= 2816 * 512;
        if (i < 512 * 1408) {
            int cc = i / 1408, j = i % 1408;
            float v = (j < 1365) ? Wout[j * 512 + cc] * cg[j] : 0.f;
            woutt[i] = f2bf(v); return;
        }
        return;
    }
    if (bid < 14720) {
        int c = ((bid - 14592) << 2) + (tid >> 6);
        int lane = tid & 63;
        float s = 0.f;
        for (int j = lane; j < 1365; j += 64) s += Wout[j * 512 + c] * cg[j];
        for (int off = 32; off; off >>= 1) s += __shfl_xor(s, off);
        if (lane == 0) ssum[c] = s;
        return;
    }
    {
        int rc = bid - 14720;
        int ti = rc >> 4, tj = rc & 15;
        int j = tid;
        float r = (float)(ti - tj);
        float rl = (r > 0.f) ? logf(r + 1.f) : ((r < 0.f) ? -logf(1.f - r) : 0.f);
        float a = rl * w1[j] + b1[j];
        h1[j] = a / (1.f + __expf(-a));
        __syncthreads();
        float acc = b2[j];
        for (int k = 0; k < 256; ++k) acc += h1[k] * w2[k * 256 + j];
        h2[j] = acc / (1.f + __expf(-acc));
        __syncthreads();
        if (j < 8) {
            float ab = b3[j];
            for (int k = 0; k < 256; ++k) ab += h2[k] * w3[k * 8 + j];
            bias[j * 256 + ti * 16 + tj] = ab;
        }
    }
}

// ---------------- generic MFMA GEMM: C[M=32768][N] = A[M][K] * B^T[N][K] ----------------
// 128x128 tile, 256 thr, single-buffer 2-barrier (proven structure) + XCD-chunked swizzle.
// EPI 0: bf16 store (qkv). EPI 1: +residual -> bf16 (x2). EPI 2: GLU + time-shifted store.
// EPI 3: inline channel-LN stats from av fragments + LN apply + residual + fp32 transpose store.
template<int EPI>
__global__ __launch_bounds__(256, 2) void gemm_bt(
    const u16* __restrict__ A, const u16* __restrict__ B, int K, int Nb,
    u16* __restrict__ outb, float* __restrict__ outf,
    const u16* __restrict__ addb,
    const float* __restrict__ ssum, int ldOut)
{
    __shared__ u16 lds[2 * 128 * 64];
    __shared__ float smr[256];          // EPI3: [0:128) mean, [128:256) rinv
    u16* lA = lds;
    u16* lB = lds + 128 * 64;
    const int tid = threadIdx.x, lane = tid & 63, w = tid >> 6;
    const int wr = w >> 1, wc = w & 1;
    const int cpx = gridDim.x >> 3;
    const int wgid = (blockIdx.x & 7) * cpx + (blockIdx.x >> 3);
    const int p0 = (wgid / Nb) * 128, n0 = (wgid % Nb) * 128;
    f32x4 acc[4][4] = {};
    float sst[4] = {}, sq[4] = {};
    for (int kt = 0; kt < K; kt += 64) {
        for (int i = 0; i < 4; ++i) {
            int rb = w * 4 + i;
            int r = rb * 8 + (lane >> 3);
            int cg = (lane & 7) ^ (r & 7);
            gload16(A + (size_t)(p0 + r) * K + (kt + cg * 8), lA + rb * 512);
            gload16(B + (size_t)(n0 + r) * K + (kt + cg * 8), lB + rb * 512);
        }
        __syncthreads();
#pragma unroll
        for (int kk = 0; kk < 2; ++kk) {
            short8 av[4], bv[4];
#pragma unroll
            for (int m = 0; m < 4; ++m) {
                int r = wr * 64 + m * 16 + (lane & 15);
                int cc = ((kk << 2) + (lane >> 4)) ^ (r & 7);
                av[m] = *(const short8*)(lA + r * 64 + cc * 8);
            }
#pragma unroll
            for (int n = 0; n < 4; ++n) {
                int r = wc * 64 + n * 16 + (lane & 15);
                int cc = ((kk << 2) + (lane >> 4)) ^ (r & 7);
                bv[n] = *(const short8*)(lB + r * 64 + cc * 8);
            }
            if constexpr (EPI == 3) {
                if (wc == 0) {
#pragma unroll
                    for (int m = 0; m < 4; ++m)
#pragma unroll
                        for (int j = 0; j < 8; ++j) {
                            float v = bf2f((u16)av[m][j]);
                            sst[m] += v; sq[m] += v * v;
                        }
                }
            }
#pragma unroll
            for (int m = 0; m < 4; ++m)
#pragma unroll
                for (int n = 0; n < 4; ++n)
                    acc[m][n] = __builtin_amdgcn_mfma_f32_16x16x32_bf16(av[m], bv[n], acc[m][n], 0, 0, 0);
        }
        __syncthreads();
    }

    if constexpr (EPI == 0 || EPI == 1) {
#pragma unroll
        for (int m = 0; m < 4; ++m)
#pragma unroll
            for (int n = 0; n < 4; ++n) {
                int row = p0 + wr * 64 + m * 16 + ((lane >> 4) << 2);
                int col = n0 + wc * 64 + n * 16 + (lane & 15);
#pragma unroll
                for (int r = 0; r < 4; ++r) {
                    float vv = acc[m][n][r];
                    if constexpr (EPI == 1) vv += bf2f(addb[(size_t)(row + r) * ldOut + col]);
                    outb[(size_t)(row + r) * ldOut + col] = f2bf(vv);
                }
            }
    } else if constexpr (EPI == 2) {
#pragma unroll
        for (int m = 0; m < 4; ++m)
#pragma unroll
            for (int np = 0; np < 2; ++np) {
                int nv = np << 1;
                int colBase = n0 + wc * 64 + nv * 16 + (lane & 15);
                int jj = ((colBase >> 5) << 4) + (colBase & 15);
                int rowb = p0 + wr * 64 + m * 16 + ((lane >> 4) << 2);
                int t = (rowb >> 10) & 15;
#pragma unroll
                for (int r = 0; r < 4; ++r) {
                    int p = rowb + r;
                    float vv = acc[m][nv][r], gv = acc[m][nv + 1][r];
                    float glu = vv * 0.5f * gv * (1.f + erff(gv * 0.70710678f));
                    if (jj >= 1365) {
                        outb[(size_t)p * 1408 + jj] = 0;           // K-pad cols, always zero
                    } else if (jj >= 683) {
                        if (t < 15) outb[(size_t)(p + 1024) * 1408 + jj] = f2bf(glu); // time shift
                        if (t == 0) outb[(size_t)p * 1408 + jj] = 0;                  // shifted-in zeros
                    } else {
                        outb[(size_t)p * 1408 + jj] = f2bf(glu);
                    }
                }
            }
    } else {
        // EPI 3: finish inline stats, then channel-LN apply + residual + transposed fp32 store
        if (wc == 0) {
#pragma unroll
            for (int m = 0; m < 4; ++m) {
                float s = sst[m], q = sq[m];
                s += __shfl_xor(s, 16); q += __shfl_xor(q, 16);
                s += __shfl_xor(s, 32); q += __shfl_xor(q, 32);
                if ((lane >> 4) == 0) {
                    int row = wr * 64 + m * 16 + (lane & 15);
                    smr[row] = s; smr[128 + row] = q;
                }
            }
        }
        __syncthreads();
        if (tid < 128) {
            float mm = smr[tid] * (1.f / 1365.f);
            float var = smr[128 + tid] * (1.f / 1365.f) - mm * mm;
            smr[tid] = mm;
            smr[128 + tid] = rsqrtf(fmaxf(var, 1e-5f));
        }
        float* ldsT = (float*)lds;
        const int bb = p0 >> 14, tt = (p0 >> 10) & 15, hwb = p0 & 1023;
        float* outp = outf + (size_t)bb * 8388608 + (size_t)tt * 1024 + hwb;
        for (int cg4 = 0; cg4 < 4; ++cg4) {
            __syncthreads();
            if (wc == (cg4 >> 1)) {
#pragma unroll
                for (int m = 0; m < 4; ++m)
#pragma unroll
                    for (int nn = 0; nn < 2; ++nn) {
                        int n = ((cg4 & 1) << 1) + nn;
                        int cl2 = (nn << 4) + (lane & 15);
                        int col = n0 + wc * 64 + n * 16 + (lane & 15);
                        int rl = wr * 64 + m * 16 + ((lane >> 4) << 2);
                        float ssv = ssum[col];
#pragma unroll
                        for (int r = 0; r < 4; ++r) {
                            int p = p0 + rl + r;
                            float vv = smr[128 + rl + r] * (acc[m][n][r] - smr[rl + r] * ssv)
                                     + bf2f(addb[(size_t)p * 512 + col]);
                            ldsT[cl2 * 132 + rl + r] = vv;
                        }
                    }
            }
            __syncthreads();
#pragma unroll
            for (int e = 0; e < 16; ++e) {
                int li = e * 256 + tid;
                int cl2 = li >> 7, hwl = li & 127;
                outp[(size_t)(n0 + cg4 * 32 + cl2) * 16384 + hwl] = ldsT[cl2 * 132 + hwl];
            }
        }
    }
}

// ---------------- attention: per (8-pixel chunk, head) block; 2 blocks/CU ----------------
__global__ __launch_bounds__(256, 2) void attn_kernel(
    const u16* __restrict__ qkv, const float* __restrict__ bias, u16* __restrict__ o)
{
    __shared__ u16 qkvt[3 * 128 * 64];
    __shared__ float pl[128 * 17];
    __shared__ float bl[256];
    const int tid = threadIdx.x, lane = tid & 63, w = tid >> 6;
    const int pc = blockIdx.x, h = blockIdx.y;
    const int b = pc >> 7, hw0 = (pc & 127) << 3;
    bl[tid] = bias[h * 256 + tid];
    for (int i = 0; i < 12; ++i) {
        int idx = w * 12 + i;
        int s = idx >> 4, rb = idx & 15;
        int r = (rb << 3) + (lane >> 3);
        int cg = (lane & 7) ^ (r & 7);
        size_t grow = (size_t)b * 16384 + (size_t)(r >> 3) * 1024 + hw0 + (r & 7);
        gload16(qkv + grow * 1536 + s * 512 + h * 64 + cg * 8, qkvt + s * 8192 + rb * 512);
    }
    __syncthreads();
    {
        const int qrow = tid & 127, hh = tid >> 7;
        const int pix = qrow & 7, ti = qrow >> 3;
        float qv[64];
        const u16* qr = qkvt + qrow * 64;
#pragma unroll
        for (int cc = 0; cc < 8; ++cc) {
            short8 qq = *(const short8*)(qr + ((cc ^ (qrow & 7)) << 3));
#pragma unroll
            for (int j = 0; j < 8; ++j) qv[cc * 8 + j] = bf2f((u16)qq[j]);
        }
#pragma unroll
        for (int tj8 = 0; tj8 < 8; ++tj8) {
            int tj = (hh << 3) + tj8;
            int rk = (tj << 3) + pix;
            const u16* kr = qkvt + 8192 + rk * 64;
            float a = 0.f;
#pragma unroll
            for (int cc = 0; cc < 8; ++cc) {
                short8 kk = *(const short8*)(kr + ((cc ^ (rk & 7)) << 3));
#pragma unroll
                for (int j = 0; j < 8; ++j) a += qv[cc * 8 + j] * bf2f((u16)kk[j]);
            }
            pl[qrow * 17 + tj] = a * 0.125f + bl[(ti << 4) + tj];
        }
    }
    __syncthreads();
    if (tid < 128) {
        float sc[16];
#pragma unroll
        for (int j = 0; j < 16; ++j) sc[j] = pl[tid * 17 + j];
        float mx = sc[0];
#pragma unroll
        for (int j = 1; j < 16; ++j) mx = fmaxf(mx, sc[j]);
        float sum = 0.f;
#pragma unroll
        for (int j = 0; j < 16; ++j) { sc[j] = __expf(sc[j] - mx); sum += sc[j]; }
        float inv = 1.f / sum;
#pragma unroll
        for (int j = 0; j < 16; ++j) pl[tid * 17 + j] = sc[j] * inv;
    }
    __syncthreads();
    {
        const int pix = tid >> 5, dg = tid & 31;
        float v0[16], v1[16];
#pragma unroll
        for (int tj = 0; tj < 16; ++tj) {
            int rv = (tj << 3) + pix;
            unsigned int d = *(const unsigned int*)(qkvt + 16384 + rv * 64 +
                               (((dg >> 2) ^ (rv & 7)) << 3) + ((dg & 3) << 1));
            v0[tj] = bf2f((u16)(d & 0xffff));
            v1[tj] = bf2f((u16)(d >> 16));
        }
#pragma unroll
        for (int ti = 0; ti < 16; ++ti) {
            float a0 = 0.f, a1 = 0.f;
            const float* pr = pl + ((ti << 3) + pix) * 17;
#pragma unroll
            for (int tj = 0; tj < 16; ++tj) {
                float pv = pr[tj];
                a0 += pv * v0[tj];
                a1 += pv * v1[tj];
            }
            size_t p = (size_t)b * 16384 + (size_t)ti * 1024 + hw0 + pix;
            unsigned int pk = (unsigned int)f2bf(a0) | ((unsigned int)f2bf(a1) << 16);
            *(unsigned int*)(o + p * 512 + h * 64 + (dg << 1)) = pk;
        }
    }
}

extern "C" void kernel_launch(void* const* d_in, const int* in_sizes, int n_in,
                              void* d_out, int out_size, void* d_ws, size_t ws_size,
                              hipStream_t stream)
{
    const float* x       = (const float*)d_in[0];
    const int*   frp     = (const int*)d_in[1];
    const float* g_norm  = (const float*)d_in[2];
    const float* Wq      = (const float*)d_in[3];
    const float* Wkv     = (const float*)d_in[4];
    const float* Wo      = (const float*)d_in[5];
    const float* pos_emb = (const float*)d_in[6];
    const float* fr_emb  = (const float*)d_in[7];
    const float* w1      = (const float*)d_in[8];
    const float* b1      = (const float*)d_in[9];
    const float* w2      = (const float*)d_in[10];
    const float* b2      = (const float*)d_in[11];
    const float* w3      = (const float*)d_in[12];
    const float* b3      = (const float*)d_in[13];
    const float* Win     = (const float*)d_in[14];
    const float* chan_g  = (const float*)d_in[15];
    const float* Wout    = (const float*)d_in[16];

    char* ws = (char*)d_ws;
    u16*   wqkvt = (u16*)(ws + 0);
    u16*   wot   = (u16*)(ws + 1572864);
    u16*   winp  = (u16*)(ws + 2097152);
    u16*   woutt = (u16*)(ws + 4980736);
    float* ssum  = (float*)(ws + 6422528);
    float* biasb = (float*)(ws + 6424576);
    u16*   qkv   = (u16*)(ws + 8388608);     // reused as yg after attention
    u16*   xn    = (u16*)(ws + 109051904);   // reused as o_att after qkv GEMM
    u16*   xt    = (u16*)(ws + 142606336);
    u16*   x2    = (u16*)(ws + 176160768);
    u16*   o_att = xn;
    u16*   yg    = qkv;

    prologue_all<<<14976, 256, 0, stream>>>(
        x, frp, g_norm, pos_emb, fr_emb,
        Wq, Wkv, Wo, Win, Wout, chan_g, w1, b1, w2, b2, w3, b3,
        xn, xt, wqkvt, wot, winp, woutt, ssum, biasb);
    gemm_bt<0><<<256 * 12, 256, 0, stream>>>(xn, wqkvt, 512, 12, qkv, nullptr, nullptr,
                                             nullptr, 1536);
    attn_kernel<<<dim3(256, 8), 256, 0, stream>>>(qkv, biasb, o_att);
    gemm_bt<1><<<256 * 4, 256, 0, stream>>>(o_att, wot, 512, 4, x2, nullptr, xt,
                                            nullptr, 512);
    gemm_bt<2><<<256 * 22, 256, 0, stream>>>(x2, winp, 512, 22, yg, nullptr, nullptr,
                                             nullptr, 1408);
    gemm_bt<3><<<256 * 4, 256, 0, stream>>>(yg, woutt, 1408, 4, nullptr, (float*)d_out, x2,
                                            ssum, 512);
}

// Round 9
// 405.722 us; speedup vs baseline: 1.1429x; 1.0273x over previous
//
#include <hip/hip_runtime.h>

using u16 = unsigned short;
using f32x4 = __attribute__((ext_vector_type(4))) float;
using short8 = __attribute__((ext_vector_type(8))) short;

__device__ __forceinline__ float bf2f(u16 u) {
    union { unsigned int i; float f; } v; v.i = ((unsigned int)u) << 16; return v.f;
}
__device__ __forceinline__ u16 f2bf(float f) {
    union { float f; unsigned int i; } v; v.f = f;
    unsigned int u = v.i;
    u += 0x7fffu + ((u >> 16) & 1u);
    return (u16)(u >> 16);
}
__device__ __forceinline__ void gload16(const u16* g, u16* l) {
    __builtin_amdgcn_global_load_lds((const __attribute__((address_space(1))) void*)g,
                                     (__attribute__((address_space(3))) void*)l, 16, 0, 0);
}

// ---------------- fused prologue ----------------
// blocks [0,2048): k1 temporal-LN (vectorized uint2 stores)
// [2048,2240): wqkvt transpose  [2240,2304): wot  [2304,2656): winp  [2656,2832): woutt
//   (64x64 LDS tiles: coalesced loads, pad-65 float tile, packed uint2 bf16 stores)
// [2832,2960): ssum   [2960,3216): bias MLP
__global__ __launch_bounds__(256) void prologue_all(
    const float* __restrict__ x, const int* __restrict__ frp,
    const float* __restrict__ g_norm, const float* __restrict__ pos_emb,
    const float* __restrict__ fr_emb,
    const float* __restrict__ Wq, const float* __restrict__ Wkv,
    const float* __restrict__ Wo, const float* __restrict__ Win,
    const float* __restrict__ Wout, const float* __restrict__ cg,
    const float* __restrict__ w1, const float* __restrict__ b1,
    const float* __restrict__ w2, const float* __restrict__ b2,
    const float* __restrict__ w3, const float* __restrict__ b3,
    u16* __restrict__ xn, u16* __restrict__ xt,
    u16* __restrict__ wqkvt, u16* __restrict__ wot,
    u16* __restrict__ winp, u16* __restrict__ woutt,
    float* __restrict__ ssum, float* __restrict__ bias)
{
    __shared__ __align__(16) char smem[256 * 36 * 2];   // 18.4 KB pool (k1 tile / 64x65 float tile / bias h1,h2)
    const int bid = blockIdx.x;
    const int tid = threadIdx.x;
    if (bid < 2048) {
        // ---- k1: temporal LayerNorm, write xn & xt token-major bf16 ----
        u16* tile = (u16*)smem;                          // [256][36]
        const int b = bid >> 10, rem = bid & 1023;
        const int hw0 = (rem >> 4) << 4;
        const int c0 = (rem & 15) << 5;
        const int hwl = tid & 15, cl = tid >> 4;
        const int fr = frp[0] - 1;
        float v[2][16], mean2[2], ri2[2], gg2[2], fv2[2];
        for (int cp = 0; cp < 2; ++cp) {
            const int c = c0 + cl + (cp << 4);
            const float* xp = x + (size_t)(b * 512 + c) * 16384 + hw0 + hwl;
            const float fv = fr_emb[fr * 512 + c];
            float s1 = 0.f, s2 = 0.f;
#pragma unroll
            for (int t = 0; t < 16; ++t) {
                float xv = xp[t * 1024];
                v[cp][t] = xv;
                float xe = xv + pos_emb[t * 512 + c] + fv;
                s1 += xe; s2 += xe * xe;
            }
            float m = s1 * 0.0625f;
            float var = s2 * 0.0625f - m * m;
            mean2[cp] = m; ri2[cp] = rsqrtf(fmaxf(var, 1e-5f));
            gg2[cp] = g_norm[c]; fv2[cp] = fv;
        }
        for (int cp = 0; cp < 2; ++cp) {
            const int c = c0 + cl + (cp << 4);
#pragma unroll
            for (int t = 0; t < 16; ++t) {
                float xe = v[cp][t] + pos_emb[t * 512 + c] + fv2[cp];
                tile[((t << 4) + hwl) * 36 + cl + (cp << 4)] = f2bf((xe - mean2[cp]) * ri2[cp] * gg2[cp]);
            }
        }
        __syncthreads();
        for (int it = 0; it < 8; ++it) {
            int idx = it * 256 + tid;
            int rowl = idx >> 3, c4 = (idx & 7) << 2;
            size_t p = (size_t)b * 16384 + (size_t)(rowl >> 4) * 1024 + hw0 + (rowl & 15);
            uint2 d = *(const uint2*)(tile + rowl * 36 + c4);
            *(uint2*)(xn + p * 512 + c0 + c4) = d;
        }
        __syncthreads();
        for (int cp = 0; cp < 2; ++cp)
#pragma unroll
            for (int t = 0; t < 16; ++t)
                tile[((t << 4) + hwl) * 36 + cl + (cp << 4)] = f2bf(v[cp][t]);
        __syncthreads();
        for (int it = 0; it < 8; ++it) {
            int idx = it * 256 + tid;
            int rowl = idx >> 3, c4 = (idx & 7) << 2;
            size_t p = (size_t)b * 16384 + (size_t)(rowl >> 4) * 1024 + hw0 + (rowl & 15);
            uint2 d = *(const uint2*)(tile + rowl * 36 + c4);
            *(uint2*)(xt + p * 512 + c0 + c4) = d;
        }
        return;
    }
    if (bid < 2832) {
        // ---- tiled weight transposes: out[r][c] over 64x64 tiles ----
        float* tf = (float*)smem;                        // [64][65]
        const u16* dummy = nullptr; (void)dummy;
        int r0, c0, ldout;
        u16* dst;
        int kind;
        int tt;
        if (bid < 2240)      { tt = bid - 2048; r0 = (tt >> 3) << 6; c0 = (tt & 7) << 6;  dst = wqkvt; ldout = 512;  kind = 0; }
        else if (bid < 2304) { tt = bid - 2240; r0 = (tt >> 3) << 6; c0 = (tt & 7) << 6;  dst = wot;   ldout = 512;  kind = 1; }
        else if (bid < 2656) { tt = bid - 2304; r0 = (tt >> 3) << 6; c0 = (tt & 7) << 6;  dst = winp;  ldout = 512;  kind = 2; }
        else                 { tt = bid - 2656; r0 = (tt / 22) << 6; c0 = (tt % 22) << 6; dst = woutt; ldout = 1408; kind = 3; }
#pragma unroll 1
        for (int i = 0; i < 16; ++i) {
            int idx = tid + (i << 8);
            int cl = idx >> 6, rl = idx & 63;
            int r = r0 + rl, c = c0 + cl;
            float v;
            if (kind == 0) {
                v = (r < 512) ? Wq[c * 512 + r] : Wkv[c * 1024 + (r - 512)];
            } else if (kind == 1) {
                v = Wo[c * 512 + r];
            } else if (kind == 2) {
                int jj = ((r >> 5) << 4) + (r & 15);
                int gate = (r >> 4) & 1;
                v = (jj < 1365) ? Win[c * 2730 + jj + gate * 1365] : 0.f;
            } else {
                v = (c < 1365) ? Wout[c * 512 + r] * cg[c] : 0.f;
            }
            tf[rl * 65 + cl] = v;
        }
        __syncthreads();
        for (int i = 0; i < 4; ++i) {
            int idx = tid + (i << 8);
            int rl = idx >> 4, c4 = (idx & 15) << 2;
            const float* tp = tf + rl * 65 + c4;
            unsigned int lo = ((unsigned int)f2bf(tp[1]) << 16) | f2bf(tp[0]);
            unsigned int hi = ((unsigned int)f2bf(tp[3]) << 16) | f2bf(tp[2]);
            *(uint2*)(dst + (size_t)(r0 + rl) * ldout + c0 + c4) = make_uint2(lo, hi);
        }
        return;
    }
    if (bid < 2960) {
        int c = ((bid - 2832) << 2) + (tid >> 6);
        int lane = tid & 63;
        float s = 0.f;
        for (int j = lane; j < 1365; j += 64) s += Wout[j * 512 + c] * cg[j];
        for (int off = 32; off; off >>= 1) s += __shfl_xor(s, off);
        if (lane == 0) ssum[c] = s;
        return;
    }
    {
        float* h1 = (float*)smem;
        float* h2 = h1 + 256;
        int rc = bid - 2960;
        int ti = rc >> 4, tj = rc & 15;
        int j = tid;
        float r = (float)(ti - tj);
        float rl = (r > 0.f) ? logf(r + 1.f) : ((r < 0.f) ? -logf(1.f - r) : 0.f);
        float a = rl * w1[j] + b1[j];
        h1[j] = a / (1.f + __expf(-a));
        __syncthreads();
        float acc = b2[j];
        for (int k = 0; k < 256; ++k) acc += h1[k] * w2[k * 256 + j];
        h2[j] = acc / (1.f + __expf(-acc));
        __syncthreads();
        if (j < 8) {
            float ab = b3[j];
            for (int k = 0; k < 256; ++k) ab += h2[k] * w3[k * 8 + j];
            bias[j * 256 + ti * 16 + tj] = ab;
        }
    }
}

// ---------------- generic MFMA GEMM: C[M=32768][N] = A[M][K] * B^T[N][K] ----------------
// 128x128 tile, 256 thr, single-buffer 2-barrier (proven structure) + XCD-chunked swizzle.
// EPI 0: bf16 store (qkv). EPI 1: +residual -> bf16 (x2). EPI 2: GLU + time-shifted store.
// EPI 3: inline channel-LN stats from av fragments + LN apply + residual + fp32 transpose store.
template<int EPI>
__global__ __launch_bounds__(256, 2) void gemm_bt(
    const u16* __restrict__ A, const u16* __restrict__ B, int K, int Nb,
    u16* __restrict__ outb, float* __restrict__ outf,
    const u16* __restrict__ addb,
    const float* __restrict__ ssum, int ldOut)
{
    __shared__ u16 lds[2 * 128 * 64];
    __shared__ float smr[256];          // EPI3: [0:128) mean, [128:256) rinv
    u16* lA = lds;
    u16* lB = lds + 128 * 64;
    const int tid = threadIdx.x, lane = tid & 63, w = tid >> 6;
    const int wr = w >> 1, wc = w & 1;
    const int cpx = gridDim.x >> 3;
    const int wgid = (blockIdx.x & 7) * cpx + (blockIdx.x >> 3);
    const int p0 = (wgid / Nb) * 128, n0 = (wgid % Nb) * 128;
    f32x4 acc[4][4] = {};
    float sst[4] = {}, sq[4] = {};
    for (int kt = 0; kt < K; kt += 64) {
        for (int i = 0; i < 4; ++i) {
            int rb = w * 4 + i;
            int r = rb * 8 + (lane >> 3);
            int cg = (lane & 7) ^ (r & 7);
            gload16(A + (size_t)(p0 + r) * K + (kt + cg * 8), lA + rb * 512);
            gload16(B + (size_t)(n0 + r) * K + (kt + cg * 8), lB + rb * 512);
        }
        __syncthreads();
#pragma unroll
        for (int kk = 0; kk < 2; ++kk) {
            short8 av[4], bv[4];
#pragma unroll
            for (int m = 0; m < 4; ++m) {
                int r = wr * 64 + m * 16 + (lane & 15);
                int cc = ((kk << 2) + (lane >> 4)) ^ (r & 7);
                av[m] = *(const short8*)(lA + r * 64 + cc * 8);
            }
#pragma unroll
            for (int n = 0; n < 4; ++n) {
                int r = wc * 64 + n * 16 + (lane & 15);
                int cc = ((kk << 2) + (lane >> 4)) ^ (r & 7);
                bv[n] = *(const short8*)(lB + r * 64 + cc * 8);
            }
            if constexpr (EPI == 3) {
                if (wc == 0) {
#pragma unroll
                    for (int m = 0; m < 4; ++m)
#pragma unroll
                        for (int j = 0; j < 8; ++j) {
                            float v = bf2f((u16)av[m][j]);
                            sst[m] += v; sq[m] += v * v;
                        }
                }
            }
#pragma unroll
            for (int m = 0; m < 4; ++m)
#pragma unroll
                for (int n = 0; n < 4; ++n)
                    acc[m][n] = __builtin_amdgcn_mfma_f32_16x16x32_bf16(av[m], bv[n], acc[m][n], 0, 0, 0);
        }
        __syncthreads();
    }

    if constexpr (EPI == 0 || EPI == 1) {
#pragma unroll
        for (int m = 0; m < 4; ++m)
#pragma unroll
            for (int n = 0; n < 4; ++n) {
                int row = p0 + wr * 64 + m * 16 + ((lane >> 4) << 2);
                int col = n0 + wc * 64 + n * 16 + (lane & 15);
#pragma unroll
                for (int r = 0; r < 4; ++r) {
                    float vv = acc[m][n][r];
                    if constexpr (EPI == 1) vv += bf2f(addb[(size_t)(row + r) * ldOut + col]);
                    outb[(size_t)(row + r) * ldOut + col] = f2bf(vv);
                }
            }
    } else if constexpr (EPI == 2) {
#pragma unroll
        for (int m = 0; m < 4; ++m)
#pragma unroll
            for (int np = 0; np < 2; ++np) {
                int nv = np << 1;
                int colBase = n0 + wc * 64 + nv * 16 + (lane & 15);
                int jj = ((colBase >> 5) << 4) + (colBase & 15);
                int rowb = p0 + wr * 64 + m * 16 + ((lane >> 4) << 2);
                int t = (rowb >> 10) & 15;
#pragma unroll
                for (int r = 0; r < 4; ++r) {
                    int p = rowb + r;
                    float vv = acc[m][nv][r], gv = acc[m][nv + 1][r];
                    float glu = vv * 0.5f * gv * (1.f + erff(gv * 0.70710678f));
                    if (jj >= 1365) {
                        outb[(size_t)p * 1408 + jj] = 0;           // K-pad cols, always zero
                    } else if (jj >= 683) {
                        if (t < 15) outb[(size_t)(p + 1024) * 1408 + jj] = f2bf(glu); // time shift
                        if (t == 0) outb[(size_t)p * 1408 + jj] = 0;                  // shifted-in zeros
                    } else {
                        outb[(size_t)p * 1408 + jj] = f2bf(glu);
                    }
                }
            }
    } else {
        // EPI 3: finish inline stats, then channel-LN apply + residual + transposed fp32 store
        if (wc == 0) {
#pragma unroll
            for (int m = 0; m < 4; ++m) {
                float s = sst[m], q = sq[m];
                s += __shfl_xor(s, 16); q += __shfl_xor(q, 16);
                s += __shfl_xor(s, 32); q += __shfl_xor(q, 32);
                if ((lane >> 4) == 0) {
                    int row = wr * 64 + m * 16 + (lane & 15);
                    smr[row] = s; smr[128 + row] = q;
                }
            }
        }
        __syncthreads();
        if (tid < 128) {
            float mm = smr[tid] * (1.f / 1365.f);
            float var = smr[128 + tid] * (1.f / 1365.f) - mm * mm;
            smr[tid] = mm;
            smr[128 + tid] = rsqrtf(fmaxf(var, 1e-5f));
        }
        float* ldsT = (float*)lds;
        const int bb = p0 >> 14, tt = (p0 >> 10) & 15, hwb = p0 & 1023;
        float* outp = outf + (size_t)bb * 8388608 + (size_t)tt * 1024 + hwb;
        for (int cg4 = 0; cg4 < 4; ++cg4) {
            __syncthreads();
            if (wc == (cg4 >> 1)) {
#pragma unroll
                for (int m = 0; m < 4; ++m)
#pragma unroll
                    for (int nn = 0; nn < 2; ++nn) {
                        int n = ((cg4 & 1) << 1) + nn;
                        int cl2 = (nn << 4) + (lane & 15);
                        int col = n0 + wc * 64 + n * 16 + (lane & 15);
                        int rl = wr * 64 + m * 16 + ((lane >> 4) << 2);
                        float ssv = ssum[col];
#pragma unroll
                        for (int r = 0; r < 4; ++r) {
                            int p = p0 + rl + r;
                            float vv = smr[128 + rl + r] * (acc[m][n][r] - smr[rl + r] * ssv)
                                     + bf2f(addb[(size_t)p * 512 + col]);
                            ldsT[cl2 * 132 + rl + r] = vv;
                        }
                    }
            }
            __syncthreads();
#pragma unroll
            for (int e = 0; e < 16; ++e) {
                int li = e * 256 + tid;
                int cl2 = li >> 7, hwl = li & 127;
                outp[(size_t)(n0 + cg4 * 32 + cl2) * 16384 + hwl] = ldsT[cl2 * 132 + hwl];
            }
        }
    }
}

// ---------------- attention: per (8-pixel chunk, head) block; 2 blocks/CU ----------------
__global__ __launch_bounds__(256, 2) void attn_kernel(
    const u16* __restrict__ qkv, const float* __restrict__ bias, u16* __restrict__ o)
{
    __shared__ u16 qkvt[3 * 128 * 64];
    __shared__ float pl[128 * 17];
    __shared__ float bl[256];
    const int tid = threadIdx.x, lane = tid & 63, w = tid >> 6;
    const int pc = blockIdx.x, h = blockIdx.y;
    const int b = pc >> 7, hw0 = (pc & 127) << 3;
    bl[tid] = bias[h * 256 + tid];
    for (int i = 0; i < 12; ++i) {
        int idx = w * 12 + i;
        int s = idx >> 4, rb = idx & 15;
        int r = (rb << 3) + (lane >> 3);
        int cg = (lane & 7) ^ (r & 7);
        size_t grow = (size_t)b * 16384 + (size_t)(r >> 3) * 1024 + hw0 + (r & 7);
        gload16(qkv + grow * 1536 + s * 512 + h * 64 + cg * 8, qkvt + s * 8192 + rb * 512);
    }
    __syncthreads();
    {
        const int qrow = tid & 127, hh = tid >> 7;
        const int pix = qrow & 7, ti = qrow >> 3;
        float qv[64];
        const u16* qr = qkvt + qrow * 64;
#pragma unroll
        for (int cc = 0; cc < 8; ++cc) {
            short8 qq = *(const short8*)(qr + ((cc ^ (qrow & 7)) << 3));
#pragma unroll
            for (int j = 0; j < 8; ++j) qv[cc * 8 + j] = bf2f((u16)qq[j]);
        }
#pragma unroll
        for (int tj8 = 0; tj8 < 8; ++tj8) {
            int tj = (hh << 3) + tj8;
            int rk = (tj << 3) + pix;
            const u16* kr = qkvt + 8192 + rk * 64;
            float a = 0.f;
#pragma unroll
            for (int cc = 0; cc < 8; ++cc) {
                short8 kk = *(const short8*)(kr + ((cc ^ (rk & 7)) << 3));
#pragma unroll
                for (int j = 0; j < 8; ++j) a += qv[cc * 8 + j] * bf2f((u16)kk[j]);
            }
            pl[qrow * 17 + tj] = a * 0.125f + bl[(ti << 4) + tj];
        }
    }
    __syncthreads();
    if (tid < 128) {
        float sc[16];
#pragma unroll
        for (int j = 0; j < 16; ++j) sc[j] = pl[tid * 17 + j];
        float mx = sc[0];
#pragma unroll
        for (int j = 1; j < 16; ++j) mx = fmaxf(mx, sc[j]);
        float sum = 0.f;
#pragma unroll
        for (int j = 0; j < 16; ++j) { sc[j] = __expf(sc[j] - mx); sum += sc[j]; }
        float inv = 1.f / sum;
#pragma unroll
        for (int j = 0; j < 16; ++j) pl[tid * 17 + j] = sc[j] * inv;
    }
    __syncthreads();
    {
        const int pix = tid >> 5, dg = tid & 31;
        float v0[16], v1[16];
#pragma unroll
        for (int tj = 0; tj < 16; ++tj) {
            int rv = (tj << 3) + pix;
            unsigned int d = *(const unsigned int*)(qkvt + 16384 + rv * 64 +
                               (((dg >> 2) ^ (rv & 7)) << 3) + ((dg & 3) << 1));
            v0[tj] = bf2f((u16)(d & 0xffff));
            v1[tj] = bf2f((u16)(d >> 16));
        }
#pragma unroll
        for (int ti = 0; ti < 16; ++ti) {
            float a0 = 0.f, a1 = 0.f;
            const float* pr = pl + ((ti << 3) + pix) * 17;
#pragma unroll
            for (int tj = 0; tj < 16; ++tj) {
                float pv = pr[tj];
                a0 += pv * v0[tj];
                a1 += pv * v1[tj];
            }
            size_t p = (size_t)b * 16384 + (size_t)ti * 1024 + hw0 + pix;
            unsigned int pk = (unsigned int)f2bf(a0) | ((unsigned int)f2bf(a1) << 16);
            *(unsigned int*)(o + p * 512 + h * 64 + (dg << 1)) = pk;
        }
    }
}

extern "C" void kernel_launch(void* const* d_in, const int* in_sizes, int n_in,
                              void* d_out, int out_size, void* d_ws, size_t ws_size,
                              hipStream_t stream)
{
    const float* x       = (const float*)d_in[0];
    const int*   frp     = (const int*)d_in[1];
    const float* g_norm  = (const float*)d_in[2];
    const float* Wq      = (const float*)d_in[3];
    const float* Wkv     = (const float*)d_in[4];
    const float* Wo      = (const float*)d_in[5];
    const float* pos_emb = (const float*)d_in[6];
    const float* fr_emb  = (const float*)d_in[7];
    const float* w1      = (const float*)d_in[8];
    const float* b1      = (const float*)d_in[9];
    const float* w2      = (const float*)d_in[10];
    const float* b2      = (const float*)d_in[11];
    const float* w3      = (const float*)d_in[12];
    const float* b3      = (const float*)d_in[13];
    const float* Win     = (const float*)d_in[14];
    const float* chan_g  = (const float*)d_in[15];
    const float* Wout    = (const float*)d_in[16];

    char* ws = (char*)d_ws;
    u16*   wqkvt = (u16*)(ws + 0);
    u16*   wot   = (u16*)(ws + 1572864);
    u16*   winp  = (u16*)(ws + 2097152);
    u16*   woutt = (u16*)(ws + 4980736);
    float* ssum  = (float*)(ws + 6422528);
    float* biasb = (float*)(ws + 6424576);
    u16*   qkv   = (u16*)(ws + 8388608);     // reused as yg after attention
    u16*   xn    = (u16*)(ws + 109051904);   // reused as o_att after qkv GEMM
    u16*   xt    = (u16*)(ws + 142606336);
    u16*   x2    = (u16*)(ws + 176160768);
    u16*   o_att = xn;
    u16*   yg    = qkv;

    prologue_all<<<3216, 256, 0, stream>>>(
        x, frp, g_norm, pos_emb, fr_emb,
        Wq, Wkv, Wo, Win, Wout, chan_g, w1, b1, w2, b2, w3, b3,
        xn, xt, wqkvt, wot, winp, woutt, ssum, biasb);
    gemm_bt<0><<<256 * 12, 256, 0, stream>>>(xn, wqkvt, 512, 12, qkv, nullptr, nullptr,
                                             nullptr, 1536);
    attn_kernel<<<dim3(256, 8), 256, 0, stream>>>(qkv, biasb, o_att);
    gemm_bt<1><<<256 * 4, 256, 0, stream>>>(o_att, wot, 512, 4, x2, nullptr, xt,
                                            nullptr, 512);
    gemm_bt<2><<<256 * 22, 256, 0, stream>>>(x2, winp, 512, 22, yg, nullptr, nullptr,
                                             nullptr, 1408);
    gemm_bt<3><<<256 * 4, 256, 0, stream>>>(yg, woutt, 1408, 4, nullptr, (float*)d_out, x2,
                                            ssum, 512);
}

// Round 10
// 402.244 us; speedup vs baseline: 1.1528x; 1.0086x over previous
//
#include <hip/hip_runtime.h>

using u16 = unsigned short;
using f32x4 = __attribute__((ext_vector_type(4))) float;
using short8 = __attribute__((ext_vector_type(8))) short;

__device__ __forceinline__ float bf2f(u16 u) {
    union { unsigned int i; float f; } v; v.i = ((unsigned int)u) << 16; return v.f;
}
__device__ __forceinline__ u16 f2bf(float f) {
    union { float f; unsigned int i; } v; v.f = f;
    unsigned int u = v.i;
    u += 0x7fffu + ((u >> 16) & 1u);
    return (u16)(u >> 16);
}
__device__ __forceinline__ void gload16(const u16* g, u16* l) {
    __builtin_amdgcn_global_load_lds((const __attribute__((address_space(1))) void*)g,
                                     (__attribute__((address_space(3))) void*)l, 16, 0, 0);
}

// ---------------- fused prologue ----------------
// blocks [0,2048): k1 temporal-LN (vectorized uint2 stores)
// [2048,2240): wqkvt transpose  [2240,2304): wot  [2304,2656): winp  [2656,2832): woutt
//   (64x64 LDS tiles: coalesced loads, pad-65 float tile, packed uint2 bf16 stores)
// [2832,2960): ssum   [2960,3216): bias MLP
__global__ __launch_bounds__(256) void prologue_all(
    const float* __restrict__ x, const int* __restrict__ frp,
    const float* __restrict__ g_norm, const float* __restrict__ pos_emb,
    const float* __restrict__ fr_emb,
    const float* __restrict__ Wq, const float* __restrict__ Wkv,
    const float* __restrict__ Wo, const float* __restrict__ Win,
    const float* __restrict__ Wout, const float* __restrict__ cg,
    const float* __restrict__ w1, const float* __restrict__ b1,
    const float* __restrict__ w2, const float* __restrict__ b2,
    const float* __restrict__ w3, const float* __restrict__ b3,
    u16* __restrict__ xn, u16* __restrict__ xt,
    u16* __restrict__ wqkvt, u16* __restrict__ wot,
    u16* __restrict__ winp, u16* __restrict__ woutt,
    float* __restrict__ ssum, float* __restrict__ bias)
{
    __shared__ __align__(16) char smem[256 * 36 * 2];   // 18.4 KB pool (k1 tile / 64x65 float tile / bias h1,h2)
    const int bid = blockIdx.x;
    const int tid = threadIdx.x;
    if (bid < 2048) {
        // ---- k1: temporal LayerNorm, write xn & xt token-major bf16 ----
        u16* tile = (u16*)smem;                          // [256][36]
        const int b = bid >> 10, rem = bid & 1023;
        const int hw0 = (rem >> 4) << 4;
        const int c0 = (rem & 15) << 5;
        const int hwl = tid & 15, cl = tid >> 4;
        const int fr = frp[0] - 1;
        float v[2][16], mean2[2], ri2[2], gg2[2], fv2[2];
        for (int cp = 0; cp < 2; ++cp) {
            const int c = c0 + cl + (cp << 4);
            const float* xp = x + (size_t)(b * 512 + c) * 16384 + hw0 + hwl;
            const float fv = fr_emb[fr * 512 + c];
            float s1 = 0.f, s2 = 0.f;
#pragma unroll
            for (int t = 0; t < 16; ++t) {
                float xv = xp[t * 1024];
                v[cp][t] = xv;
                float xe = xv + pos_emb[t * 512 + c] + fv;
                s1 += xe; s2 += xe * xe;
            }
            float m = s1 * 0.0625f;
            float var = s2 * 0.0625f - m * m;
            mean2[cp] = m; ri2[cp] = rsqrtf(fmaxf(var, 1e-5f));
            gg2[cp] = g_norm[c]; fv2[cp] = fv;
        }
        for (int cp = 0; cp < 2; ++cp) {
            const int c = c0 + cl + (cp << 4);
#pragma unroll
            for (int t = 0; t < 16; ++t) {
                float xe = v[cp][t] + pos_emb[t * 512 + c] + fv2[cp];
                tile[((t << 4) + hwl) * 36 + cl + (cp << 4)] = f2bf((xe - mean2[cp]) * ri2[cp] * gg2[cp]);
            }
        }
        __syncthreads();
        for (int it = 0; it < 8; ++it) {
            int idx = it * 256 + tid;
            int rowl = idx >> 3, c4 = (idx & 7) << 2;
            size_t p = (size_t)b * 16384 + (size_t)(rowl >> 4) * 1024 + hw0 + (rowl & 15);
            uint2 d = *(const uint2*)(tile + rowl * 36 + c4);
            *(uint2*)(xn + p * 512 + c0 + c4) = d;
        }
        __syncthreads();
        for (int cp = 0; cp < 2; ++cp)
#pragma unroll
            for (int t = 0; t < 16; ++t)
                tile[((t << 4) + hwl) * 36 + cl + (cp << 4)] = f2bf(v[cp][t]);
        __syncthreads();
        for (int it = 0; it < 8; ++it) {
            int idx = it * 256 + tid;
            int rowl = idx >> 3, c4 = (idx & 7) << 2;
            size_t p = (size_t)b * 16384 + (size_t)(rowl >> 4) * 1024 + hw0 + (rowl & 15);
            uint2 d = *(const uint2*)(tile + rowl * 36 + c4);
            *(uint2*)(xt + p * 512 + c0 + c4) = d;
        }
        return;
    }
    if (bid < 2832) {
        // ---- tiled weight transposes: out[r][c] over 64x64 tiles ----
        float* tf = (float*)smem;                        // [64][65]
        const u16* dummy = nullptr; (void)dummy;
        int r0, c0, ldout;
        u16* dst;
        int kind;
        int tt;
        if (bid < 2240)      { tt = bid - 2048; r0 = (tt >> 3) << 6; c0 = (tt & 7) << 6;  dst = wqkvt; ldout = 512;  kind = 0; }
        else if (bid < 2304) { tt = bid - 2240; r0 = (tt >> 3) << 6; c0 = (tt & 7) << 6;  dst = wot;   ldout = 512;  kind = 1; }
        else if (bid < 2656) { tt = bid - 2304; r0 = (tt >> 3) << 6; c0 = (tt & 7) << 6;  dst = winp;  ldout = 512;  kind = 2; }
        else                 { tt = bid - 2656; r0 = (tt / 22) << 6; c0 = (tt % 22) << 6; dst = woutt; ldout = 1408; kind = 3; }
#pragma unroll 1
        for (int i = 0; i < 16; ++i) {
            int idx = tid + (i << 8);
            int cl = idx >> 6, rl = idx & 63;
            int r = r0 + rl, c = c0 + cl;
            float v;
            if (kind == 0) {
                v = (r < 512) ? Wq[c * 512 + r] : Wkv[c * 1024 + (r - 512)];
            } else if (kind == 1) {
                v = Wo[c * 512 + r];
            } else if (kind == 2) {
                int jj = ((r >> 5) << 4) + (r & 15);
                int gate = (r >> 4) & 1;
                v = (jj < 1365) ? Win[c * 2730 + jj + gate * 1365] : 0.f;
            } else {
                v = (c < 1365) ? Wout[c * 512 + r] * cg[c] : 0.f;
            }
            tf[rl * 65 + cl] = v;
        }
        __syncthreads();
        for (int i = 0; i < 4; ++i) {
            int idx = tid + (i << 8);
            int rl = idx >> 4, c4 = (idx & 15) << 2;
            const float* tp = tf + rl * 65 + c4;
            unsigned int lo = ((unsigned int)f2bf(tp[1]) << 16) | f2bf(tp[0]);
            unsigned int hi = ((unsigned int)f2bf(tp[3]) << 16) | f2bf(tp[2]);
            *(uint2*)(dst + (size_t)(r0 + rl) * ldout + c0 + c4) = make_uint2(lo, hi);
        }
        return;
    }
    if (bid < 2960) {
        int c = ((bid - 2832) << 2) + (tid >> 6);
        int lane = tid & 63;
        float s = 0.f;
        for (int j = lane; j < 1365; j += 64) s += Wout[j * 512 + c] * cg[j];
        for (int off = 32; off; off >>= 1) s += __shfl_xor(s, off);
        if (lane == 0) ssum[c] = s;
        return;
    }
    {
        float* h1 = (float*)smem;
        float* h2 = h1 + 256;
        int rc = bid - 2960;
        int ti = rc >> 4, tj = rc & 15;
        int j = tid;
        float r = (float)(ti - tj);
        float rl = (r > 0.f) ? logf(r + 1.f) : ((r < 0.f) ? -logf(1.f - r) : 0.f);
        float a = rl * w1[j] + b1[j];
        h1[j] = a / (1.f + __expf(-a));
        __syncthreads();
        float acc = b2[j];
        for (int k = 0; k < 256; ++k) acc += h1[k] * w2[k * 256 + j];
        h2[j] = acc / (1.f + __expf(-acc));
        __syncthreads();
        if (j < 8) {
            float ab = b3[j];
            for (int k = 0; k < 256; ++k) ab += h2[k] * w3[k * 8 + j];
            bias[j * 256 + ti * 16 + tj] = ab;
        }
    }
}

// ---------------- generic MFMA GEMM: C[M=32768][N] = A[M][K] * B^T[N][K] ----------------
// 128x128 tile, 256 thr, single-buffer 2-barrier (proven structure) + XCD-chunked swizzle.
// EPI 0: bf16 store (qkv). EPI 1: +residual -> bf16 (x2). EPI 2: GLU + time-shifted store.
// EPI 3: inline channel-LN stats from av fragments + LN apply + residual + fp32 transpose store.
template<int EPI>
__global__ __launch_bounds__(256, 2) void gemm_bt(
    const u16* __restrict__ A, const u16* __restrict__ B, int K, int Nb,
    u16* __restrict__ outb, float* __restrict__ outf,
    const u16* __restrict__ addb,
    const float* __restrict__ ssum, int ldOut)
{
    __shared__ u16 lds[2 * 128 * 64];
    __shared__ float smr[256];          // EPI3: [0:128) mean, [128:256) rinv
    u16* lA = lds;
    u16* lB = lds + 128 * 64;
    const int tid = threadIdx.x, lane = tid & 63, w = tid >> 6;
    const int wr = w >> 1, wc = w & 1;
    const int cpx = gridDim.x >> 3;
    const int wgid = (blockIdx.x & 7) * cpx + (blockIdx.x >> 3);
    const int p0 = (wgid / Nb) * 128, n0 = (wgid % Nb) * 128;
    f32x4 acc[4][4] = {};
    float sst[4] = {}, sq[4] = {};
    for (int kt = 0; kt < K; kt += 64) {
        for (int i = 0; i < 4; ++i) {
            int rb = w * 4 + i;
            int r = rb * 8 + (lane >> 3);
            int cg = (lane & 7) ^ (r & 7);
            gload16(A + (size_t)(p0 + r) * K + (kt + cg * 8), lA + rb * 512);
            gload16(B + (size_t)(n0 + r) * K + (kt + cg * 8), lB + rb * 512);
        }
        __syncthreads();
#pragma unroll
        for (int kk = 0; kk < 2; ++kk) {
            short8 av[4], bv[4];
#pragma unroll
            for (int m = 0; m < 4; ++m) {
                int r = wr * 64 + m * 16 + (lane & 15);
                int cc = ((kk << 2) + (lane >> 4)) ^ (r & 7);
                av[m] = *(const short8*)(lA + r * 64 + cc * 8);
            }
#pragma unroll
            for (int n = 0; n < 4; ++n) {
                int r = wc * 64 + n * 16 + (lane & 15);
                int cc = ((kk << 2) + (lane >> 4)) ^ (r & 7);
                bv[n] = *(const short8*)(lB + r * 64 + cc * 8);
            }
            if constexpr (EPI == 3) {
                if (wc == 0) {
#pragma unroll
                    for (int m = 0; m < 4; ++m)
#pragma unroll
                        for (int j = 0; j < 8; ++j) {
                            float v = bf2f((u16)av[m][j]);
                            sst[m] += v; sq[m] += v * v;
                        }
                }
            }
#pragma unroll
            for (int m = 0; m < 4; ++m)
#pragma unroll
                for (int n = 0; n < 4; ++n)
                    acc[m][n] = __builtin_amdgcn_mfma_f32_16x16x32_bf16(av[m], bv[n], acc[m][n], 0, 0, 0);
        }
        __syncthreads();
    }

    if constexpr (EPI == 0 || EPI == 1) {
#pragma unroll
        for (int m = 0; m < 4; ++m)
#pragma unroll
            for (int n = 0; n < 4; ++n) {
                int row = p0 + wr * 64 + m * 16 + ((lane >> 4) << 2);
                int col = n0 + wc * 64 + n * 16 + (lane & 15);
#pragma unroll
                for (int r = 0; r < 4; ++r) {
                    float vv = acc[m][n][r];
                    if constexpr (EPI == 1) vv += bf2f(addb[(size_t)(row + r) * ldOut + col]);
                    outb[(size_t)(row + r) * ldOut + col] = f2bf(vv);
                }
            }
    } else if constexpr (EPI == 2) {
#pragma unroll
        for (int m = 0; m < 4; ++m)
#pragma unroll
            for (int np = 0; np < 2; ++np) {
                int nv = np << 1;
                int colBase = n0 + wc * 64 + nv * 16 + (lane & 15);
                int jj = ((colBase >> 5) << 4) + (colBase & 15);
                int rowb = p0 + wr * 64 + m * 16 + ((lane >> 4) << 2);
                int t = (rowb >> 10) & 15;
#pragma unroll
                for (int r = 0; r < 4; ++r) {
                    int p = rowb + r;
                    float vv = acc[m][nv][r], gv = acc[m][nv + 1][r];
                    float glu = vv * 0.5f * gv * (1.f + erff(gv * 0.70710678f));
                    if (jj >= 1365) {
                        outb[(size_t)p * 1408 + jj] = 0;           // K-pad cols, always zero
                    } else if (jj >= 683) {
                        if (t < 15) outb[(size_t)(p + 1024) * 1408 + jj] = f2bf(glu); // time shift
                        if (t == 0) outb[(size_t)p * 1408 + jj] = 0;                  // shifted-in zeros
                    } else {
                        outb[(size_t)p * 1408 + jj] = f2bf(glu);
                    }
                }
            }
    } else {
        // EPI 3: finish inline stats, then channel-LN apply + residual + transposed fp32 store
        if (wc == 0) {
#pragma unroll
            for (int m = 0; m < 4; ++m) {
                float s = sst[m], q = sq[m];
                s += __shfl_xor(s, 16); q += __shfl_xor(q, 16);
                s += __shfl_xor(s, 32); q += __shfl_xor(q, 32);
                if ((lane >> 4) == 0) {
                    int row = wr * 64 + m * 16 + (lane & 15);
                    smr[row] = s; smr[128 + row] = q;
                }
            }
        }
        __syncthreads();
        if (tid < 128) {
            float mm = smr[tid] * (1.f / 1365.f);
            float var = smr[128 + tid] * (1.f / 1365.f) - mm * mm;
            smr[tid] = mm;
            smr[128 + tid] = rsqrtf(fmaxf(var, 1e-5f));
        }
        float* ldsT = (float*)lds;
        const int bb = p0 >> 14, tt = (p0 >> 10) & 15, hwb = p0 & 1023;
        float* outp = outf + (size_t)bb * 8388608 + (size_t)tt * 1024 + hwb;
        for (int cg4 = 0; cg4 < 4; ++cg4) {
            __syncthreads();
            if (wc == (cg4 >> 1)) {
#pragma unroll
                for (int m = 0; m < 4; ++m)
#pragma unroll
                    for (int nn = 0; nn < 2; ++nn) {
                        int n = ((cg4 & 1) << 1) + nn;
                        int cl2 = (nn << 4) + (lane & 15);
                        int col = n0 + wc * 64 + n * 16 + (lane & 15);
                        int rl = wr * 64 + m * 16 + ((lane >> 4) << 2);
                        float ssv = ssum[col];
#pragma unroll
                        for (int r = 0; r < 4; ++r) {
                            int p = p0 + rl + r;
                            float vv = smr[128 + rl + r] * (acc[m][n][r] - smr[rl + r] * ssv)
                                     + bf2f(addb[(size_t)p * 512 + col]);
                            ldsT[cl2 * 132 + rl + r] = vv;
                        }
                    }
            }
            __syncthreads();
#pragma unroll
            for (int e = 0; e < 16; ++e) {
                int li = e * 256 + tid;
                int cl2 = li >> 7, hwl = li & 127;
                outp[(size_t)(n0 + cg4 * 32 + cl2) * 16384 + hwl] = ldsT[cl2 * 132 + hwl];
            }
        }
    }
}

// ---------------- attention: per (8-pixel chunk, head) block; 2 blocks/CU ----------------
__global__ __launch_bounds__(256, 2) void attn_kernel(
    const u16* __restrict__ qkv, const float* __restrict__ bias, u16* __restrict__ o)
{
    __shared__ u16 qkvt[3 * 128 * 64];
    __shared__ float pl[128 * 17];
    __shared__ float bl[256];
    const int tid = threadIdx.x, lane = tid & 63, w = tid >> 6;
    const int pc = blockIdx.x, h = blockIdx.y;
    const int b = pc >> 7, hw0 = (pc & 127) << 3;
    bl[tid] = bias[h * 256 + tid];
    for (int i = 0; i < 12; ++i) {
        int idx = w * 12 + i;
        int s = idx >> 4, rb = idx & 15;
        int r = (rb << 3) + (lane >> 3);
        int cg = (lane & 7) ^ (r & 7);
        size_t grow = (size_t)b * 16384 + (size_t)(r >> 3) * 1024 + hw0 + (r & 7);
        gload16(qkv + grow * 1536 + s * 512 + h * 64 + cg * 8, qkvt + s * 8192 + rb * 512);
    }
    __syncthreads();
    {
        const int qrow = tid & 127, hh = tid >> 7;
        const int pix = qrow & 7, ti = qrow >> 3;
        float qv[64];
        const u16* qr = qkvt + qrow * 64;
#pragma unroll
        for (int cc = 0; cc < 8; ++cc) {
            short8 qq = *(const short8*)(qr + ((cc ^ (qrow & 7)) << 3));
#pragma unroll
            for (int j = 0; j < 8; ++j) qv[cc * 8 + j] = bf2f((u16)qq[j]);
        }
#pragma unroll
        for (int tj8 = 0; tj8 < 8; ++tj8) {
            int tj = (hh << 3) + tj8;
            int rk = (tj << 3) + pix;
            const u16* kr = qkvt + 8192 + rk * 64;
            float a = 0.f;
#pragma unroll
            for (int cc = 0; cc < 8; ++cc) {
                short8 kk = *(const short8*)(kr + ((cc ^ (rk & 7)) << 3));
#pragma unroll
                for (int j = 0; j < 8; ++j) a += qv[cc * 8 + j] * bf2f((u16)kk[j]);
            }
            pl[qrow * 17 + tj] = a * 0.125f + bl[(ti << 4) + tj];
        }
    }
    __syncthreads();
    if (tid < 128) {
        float sc[16];
#pragma unroll
        for (int j = 0; j < 16; ++j) sc[j] = pl[tid * 17 + j];
        float mx = sc[0];
#pragma unroll
        for (int j = 1; j < 16; ++j) mx = fmaxf(mx, sc[j]);
        float sum = 0.f;
#pragma unroll
        for (int j = 0; j < 16; ++j) { sc[j] = __expf(sc[j] - mx); sum += sc[j]; }
        float inv = 1.f / sum;
#pragma unroll
        for (int j = 0; j < 16; ++j) pl[tid * 17 + j] = sc[j] * inv;
    }
    __syncthreads();
    {
        const int pix = tid >> 5, dg = tid & 31;
        float v0[16], v1[16];
#pragma unroll
        for (int tj = 0; tj < 16; ++tj) {
            int rv = (tj << 3) + pix;
            unsigned int d = *(const unsigned int*)(qkvt + 16384 + rv * 64 +
                               (((dg >> 2) ^ (rv & 7)) << 3) + ((dg & 3) << 1));
            v0[tj] = bf2f((u16)(d & 0xffff));
            v1[tj] = bf2f((u16)(d >> 16));
        }
#pragma unroll
        for (int ti = 0; ti < 16; ++ti) {
            float a0 = 0.f, a1 = 0.f;
            const float* pr = pl + ((ti << 3) + pix) * 17;
#pragma unroll
            for (int tj = 0; tj < 16; ++tj) {
                float pv = pr[tj];
                a0 += pv * v0[tj];
                a1 += pv * v1[tj];
            }
            size_t p = (size_t)b * 16384 + (size_t)ti * 1024 + hw0 + pix;
            unsigned int pk = (unsigned int)f2bf(a0) | ((unsigned int)f2bf(a1) << 16);
            *(unsigned int*)(o + p * 512 + h * 64 + (dg << 1)) = pk;
        }
    }
}

extern "C" void kernel_launch(void* const* d_in, const int* in_sizes, int n_in,
                              void* d_out, int out_size, void* d_ws, size_t ws_size,
                              hipStream_t stream)
{
    const float* x       = (const float*)d_in[0];
    const int*   frp     = (const int*)d_in[1];
    const float* g_norm  = (const float*)d_in[2];
    const float* Wq      = (const float*)d_in[3];
    const float* Wkv     = (const float*)d_in[4];
    const float* Wo      = (const float*)d_in[5];
    const float* pos_emb = (const float*)d_in[6];
    const float* fr_emb  = (const float*)d_in[7];
    const float* w1      = (const float*)d_in[8];
    const float* b1      = (const float*)d_in[9];
    const float* w2      = (const float*)d_in[10];
    const float* b2      = (const float*)d_in[11];
    const float* w3      = (const float*)d_in[12];
    const float* b3      = (const float*)d_in[13];
    const float* Win     = (const float*)d_in[14];
    const float* chan_g  = (const float*)d_in[15];
    const float* Wout    = (const float*)d_in[16];

    char* ws = (char*)d_ws;
    u16*   wqkvt = (u16*)(ws + 0);
    u16*   wot   = (u16*)(ws + 1572864);
    u16*   winp  = (u16*)(ws + 2097152);
    u16*   woutt = (u16*)(ws + 4980736);
    float* ssum  = (float*)(ws + 6422528);
    float* biasb = (float*)(ws + 6424576);
    u16*   qkv   = (u16*)(ws + 8388608);     // reused as yg after attention
    u16*   xn    = (u16*)(ws + 109051904);   // reused as o_att after qkv GEMM
    u16*   xt    = (u16*)(ws + 142606336);
    u16*   x2    = (u16*)(ws + 176160768);
    u16*   o_att = xn;
    u16*   yg    = qkv;

    prologue_all<<<3216, 256, 0, stream>>>(
        x, frp, g_norm, pos_emb, fr_emb,
        Wq, Wkv, Wo, Win, Wout, chan_g, w1, b1, w2, b2, w3, b3,
        xn, xt, wqkvt, wot, winp, woutt, ssum, biasb);
    gemm_bt<0><<<256 * 12, 256, 0, stream>>>(xn, wqkvt, 512, 12, qkv, nullptr, nullptr,
                                             nullptr, 1536);
    attn_kernel<<<dim3(256, 8), 256, 0, stream>>>(qkv, biasb, o_att);
    gemm_bt<1><<<256 * 4, 256, 0, stream>>>(o_att, wot, 512, 4, x2, nullptr, xt,
                                            nullptr, 512);
    gemm_bt<2><<<256 * 22, 256, 0, stream>>>(x2, winp, 512, 22, yg, nullptr, nullptr,
                                             nullptr, 1408);
    gemm_bt<3><<<256 * 4, 256, 0, stream>>>(yg, woutt, 1408, 4, nullptr, (float*)d_out, x2,
                                            ssum, 512);
}

// Round 11
// 401.283 us; speedup vs baseline: 1.1555x; 1.0024x over previous
//
#include <hip/hip_runtime.h>

using u16 = unsigned short;
using f32x4 = __attribute__((ext_vector_type(4))) float;
using short8 = __attribute__((ext_vector_type(8))) short;

__device__ __forceinline__ float bf2f(u16 u) {
    union { unsigned int i; float f; } v; v.i = ((unsigned int)u) << 16; return v.f;
}
__device__ __forceinline__ u16 f2bf(float f) {
    union { float f; unsigned int i; } v; v.f = f;
    unsigned int u = v.i;
    u += 0x7fffu + ((u >> 16) & 1u);
    return (u16)(u >> 16);
}
__device__ __forceinline__ void gload16(const u16* g, u16* l) {
    __builtin_amdgcn_global_load_lds((const __attribute__((address_space(1))) void*)g,
                                     (__attribute__((address_space(3))) void*)l, 16, 0, 0);
}

// ---------------- fused prologue ----------------
// blocks [0,2048): k1 temporal-LN (vectorized uint2 stores)
// [2048,2240): wqkvt transpose  [2240,2304): wot  [2304,2656): winp  [2656,2832): woutt
//   (64x64 LDS tiles: coalesced loads, pad-65 float tile, packed uint2 bf16 stores)
// [2832,2960): ssum   [2960,3216): bias MLP
__global__ __launch_bounds__(256) void prologue_all(
    const float* __restrict__ x, const int* __restrict__ frp,
    const float* __restrict__ g_norm, const float* __restrict__ pos_emb,
    const float* __restrict__ fr_emb,
    const float* __restrict__ Wq, const float* __restrict__ Wkv,
    const float* __restrict__ Wo, const float* __restrict__ Win,
    const float* __restrict__ Wout, const float* __restrict__ cg,
    const float* __restrict__ w1, const float* __restrict__ b1,
    const float* __restrict__ w2, const float* __restrict__ b2,
    const float* __restrict__ w3, const float* __restrict__ b3,
    u16* __restrict__ xn, u16* __restrict__ xt,
    u16* __restrict__ wqkvt, u16* __restrict__ wot,
    u16* __restrict__ winp, u16* __restrict__ woutt,
    float* __restrict__ ssum, float* __restrict__ bias)
{
    __shared__ __align__(16) char smem[256 * 36 * 2];   // 18.4 KB pool (k1 tile / 64x65 float tile / bias h1,h2)
    const int bid = blockIdx.x;
    const int tid = threadIdx.x;
    if (bid < 2048) {
        // ---- k1: temporal LayerNorm, write xn & xt token-major bf16 ----
        u16* tile = (u16*)smem;                          // [256][36]
        const int b = bid >> 10, rem = bid & 1023;
        const int hw0 = (rem >> 4) << 4;
        const int c0 = (rem & 15) << 5;
        const int hwl = tid & 15, cl = tid >> 4;
        const int fr = frp[0] - 1;
        float v[2][16], mean2[2], ri2[2], gg2[2], fv2[2];
        for (int cp = 0; cp < 2; ++cp) {
            const int c = c0 + cl + (cp << 4);
            const float* xp = x + (size_t)(b * 512 + c) * 16384 + hw0 + hwl;
            const float fv = fr_emb[fr * 512 + c];
            float s1 = 0.f, s2 = 0.f;
#pragma unroll
            for (int t = 0; t < 16; ++t) {
                float xv = xp[t * 1024];
                v[cp][t] = xv;
                float xe = xv + pos_emb[t * 512 + c] + fv;
                s1 += xe; s2 += xe * xe;
            }
            float m = s1 * 0.0625f;
            float var = s2 * 0.0625f - m * m;
            mean2[cp] = m; ri2[cp] = rsqrtf(fmaxf(var, 1e-5f));
            gg2[cp] = g_norm[c]; fv2[cp] = fv;
        }
        for (int cp = 0; cp < 2; ++cp) {
            const int c = c0 + cl + (cp << 4);
#pragma unroll
            for (int t = 0; t < 16; ++t) {
                float xe = v[cp][t] + pos_emb[t * 512 + c] + fv2[cp];
                tile[((t << 4) + hwl) * 36 + cl + (cp << 4)] = f2bf((xe - mean2[cp]) * ri2[cp] * gg2[cp]);
            }
        }
        __syncthreads();
        for (int it = 0; it < 8; ++it) {
            int idx = it * 256 + tid;
            int rowl = idx >> 3, c4 = (idx & 7) << 2;
            size_t p = (size_t)b * 16384 + (size_t)(rowl >> 4) * 1024 + hw0 + (rowl & 15);
            uint2 d = *(const uint2*)(tile + rowl * 36 + c4);
            *(uint2*)(xn + p * 512 + c0 + c4) = d;
        }
        __syncthreads();
        for (int cp = 0; cp < 2; ++cp)
#pragma unroll
            for (int t = 0; t < 16; ++t)
                tile[((t << 4) + hwl) * 36 + cl + (cp << 4)] = f2bf(v[cp][t]);
        __syncthreads();
        for (int it = 0; it < 8; ++it) {
            int idx = it * 256 + tid;
            int rowl = idx >> 3, c4 = (idx & 7) << 2;
            size_t p = (size_t)b * 16384 + (size_t)(rowl >> 4) * 1024 + hw0 + (rowl & 15);
            uint2 d = *(const uint2*)(tile + rowl * 36 + c4);
            *(uint2*)(xt + p * 512 + c0 + c4) = d;
        }
        return;
    }
    if (bid < 2832) {
        // ---- tiled weight transposes: out[r][c] over 64x64 tiles ----
        float* tf = (float*)smem;                        // [64][65]
        const u16* dummy = nullptr; (void)dummy;
        int r0, c0, ldout;
        u16* dst;
        int kind;
        int tt;
        if (bid < 2240)      { tt = bid - 2048; r0 = (tt >> 3) << 6; c0 = (tt & 7) << 6;  dst = wqkvt; ldout = 512;  kind = 0; }
        else if (bid < 2304) { tt = bid - 2240; r0 = (tt >> 3) << 6; c0 = (tt & 7) << 6;  dst = wot;   ldout = 512;  kind = 1; }
        else if (bid < 2656) { tt = bid - 2304; r0 = (tt >> 3) << 6; c0 = (tt & 7) << 6;  dst = winp;  ldout = 512;  kind = 2; }
        else                 { tt = bid - 2656; r0 = (tt / 22) << 6; c0 = (tt % 22) << 6; dst = woutt; ldout = 1408; kind = 3; }
#pragma unroll 1
        for (int i = 0; i < 16; ++i) {
            int idx = tid + (i << 8);
            int cl = idx >> 6, rl = idx & 63;
            int r = r0 + rl, c = c0 + cl;
            float v;
            if (kind == 0) {
                v = (r < 512) ? Wq[c * 512 + r] : Wkv[c * 1024 + (r - 512)];
            } else if (kind == 1) {
                v = Wo[c * 512 + r];
            } else if (kind == 2) {
                int jj = ((r >> 5) << 4) + (r & 15);
                int gate = (r >> 4) & 1;
                v = (jj < 1365) ? Win[c * 2730 + jj + gate * 1365] : 0.f;
            } else {
                v = (c < 1365) ? Wout[c * 512 + r] * cg[c] : 0.f;
            }
            tf[rl * 65 + cl] = v;
        }
        __syncthreads();
        for (int i = 0; i < 4; ++i) {
            int idx = tid + (i << 8);
            int rl = idx >> 4, c4 = (idx & 15) << 2;
            const float* tp = tf + rl * 65 + c4;
            unsigned int lo = ((unsigned int)f2bf(tp[1]) << 16) | f2bf(tp[0]);
            unsigned int hi = ((unsigned int)f2bf(tp[3]) << 16) | f2bf(tp[2]);
            *(uint2*)(dst + (size_t)(r0 + rl) * ldout + c0 + c4) = make_uint2(lo, hi);
        }
        return;
    }
    if (bid < 2960) {
        int c = ((bid - 2832) << 2) + (tid >> 6);
        int lane = tid & 63;
        float s = 0.f;
        for (int j = lane; j < 1365; j += 64) s += Wout[j * 512 + c] * cg[j];
        for (int off = 32; off; off >>= 1) s += __shfl_xor(s, off);
        if (lane == 0) ssum[c] = s;
        return;
    }
    {
        float* h1 = (float*)smem;
        float* h2 = h1 + 256;
        int rc = bid - 2960;
        int ti = rc >> 4, tj = rc & 15;
        int j = tid;
        float r = (float)(ti - tj);
        float rl = (r > 0.f) ? logf(r + 1.f) : ((r < 0.f) ? -logf(1.f - r) : 0.f);
        float a = rl * w1[j] + b1[j];
        h1[j] = a / (1.f + __expf(-a));
        __syncthreads();
        float acc = b2[j];
        for (int k = 0; k < 256; ++k) acc += h1[k] * w2[k * 256 + j];
        h2[j] = acc / (1.f + __expf(-acc));
        __syncthreads();
        if (j < 8) {
            float ab = b3[j];
            for (int k = 0; k < 256; ++k) ab += h2[k] * w3[k * 8 + j];
            bias[j * 256 + ti * 16 + tj] = ab;
        }
    }
}

// ---------------- generic MFMA GEMM: C[M=32768][N] = A[M][K] * B^T[N][K] ----------------
// 128x128 tile, 256 thr, single-buffer 2-barrier (proven structure) + XCD-chunked swizzle.
// EPI 0: bf16 store (qkv). EPI 1: +residual -> bf16 (x2). EPI 2: GLU + time-shifted store.
// EPI 3: inline channel-LN stats from av fragments + LN apply + residual + fp32 transpose store.
template<int EPI>
__global__ __launch_bounds__(256, 2) void gemm_bt(
    const u16* __restrict__ A, const u16* __restrict__ B, int K, int Nb,
    u16* __restrict__ outb, float* __restrict__ outf,
    const u16* __restrict__ addb,
    const float* __restrict__ ssum, int ldOut)
{
    __shared__ u16 lds[2 * 128 * 64];
    __shared__ float smr[256];          // EPI3: [0:128) mean, [128:256) rinv
    u16* lA = lds;
    u16* lB = lds + 128 * 64;
    const int tid = threadIdx.x, lane = tid & 63, w = tid >> 6;
    const int wr = w >> 1, wc = w & 1;
    const int cpx = gridDim.x >> 3;
    const int wgid = (blockIdx.x & 7) * cpx + (blockIdx.x >> 3);
    const int p0 = (wgid / Nb) * 128, n0 = (wgid % Nb) * 128;
    f32x4 acc[4][4] = {};
    float sst[4] = {}, sq[4] = {};
    for (int kt = 0; kt < K; kt += 64) {
        for (int i = 0; i < 4; ++i) {
            int rb = w * 4 + i;
            int r = rb * 8 + (lane >> 3);
            int cg = (lane & 7) ^ (r & 7);
            gload16(A + (size_t)(p0 + r) * K + (kt + cg * 8), lA + rb * 512);
            gload16(B + (size_t)(n0 + r) * K + (kt + cg * 8), lB + rb * 512);
        }
        __syncthreads();
#pragma unroll
        for (int kk = 0; kk < 2; ++kk) {
            short8 av[4], bv[4];
#pragma unroll
            for (int m = 0; m < 4; ++m) {
                int r = wr * 64 + m * 16 + (lane & 15);
                int cc = ((kk << 2) + (lane >> 4)) ^ (r & 7);
                av[m] = *(const short8*)(lA + r * 64 + cc * 8);
            }
#pragma unroll
            for (int n = 0; n < 4; ++n) {
                int r = wc * 64 + n * 16 + (lane & 15);
                int cc = ((kk << 2) + (lane >> 4)) ^ (r & 7);
                bv[n] = *(const short8*)(lB + r * 64 + cc * 8);
            }
            if constexpr (EPI == 3) {
                if (wc == 0) {
#pragma unroll
                    for (int m = 0; m < 4; ++m)
#pragma unroll
                        for (int j = 0; j < 8; ++j) {
                            float v = bf2f((u16)av[m][j]);
                            sst[m] += v; sq[m] += v * v;
                        }
                }
            }
#pragma unroll
            for (int m = 0; m < 4; ++m)
#pragma unroll
                for (int n = 0; n < 4; ++n)
                    acc[m][n] = __builtin_amdgcn_mfma_f32_16x16x32_bf16(av[m], bv[n], acc[m][n], 0, 0, 0);
        }
        __syncthreads();
    }

    if constexpr (EPI == 0 || EPI == 1) {
#pragma unroll
        for (int m = 0; m < 4; ++m)
#pragma unroll
            for (int n = 0; n < 4; ++n) {
                int row = p0 + wr * 64 + m * 16 + ((lane >> 4) << 2);
                int col = n0 + wc * 64 + n * 16 + (lane & 15);
#pragma unroll
                for (int r = 0; r < 4; ++r) {
                    float vv = acc[m][n][r];
                    if constexpr (EPI == 1) vv += bf2f(addb[(size_t)(row + r) * ldOut + col]);
                    outb[(size_t)(row + r) * ldOut + col] = f2bf(vv);
                }
            }
    } else if constexpr (EPI == 2) {
#pragma unroll
        for (int m = 0; m < 4; ++m)
#pragma unroll
            for (int np = 0; np < 2; ++np) {
                int nv = np << 1;
                int colBase = n0 + wc * 64 + nv * 16 + (lane & 15);
                int jj = ((colBase >> 5) << 4) + (colBase & 15);
                int rowb = p0 + wr * 64 + m * 16 + ((lane >> 4) << 2);
                int t = (rowb >> 10) & 15;
#pragma unroll
                for (int r = 0; r < 4; ++r) {
                    int p = rowb + r;
                    float vv = acc[m][nv][r], gv = acc[m][nv + 1][r];
                    float glu = vv * 0.5f * gv * (1.f + erff(gv * 0.70710678f));
                    if (jj >= 1365) {
                        outb[(size_t)p * 1408 + jj] = 0;           // K-pad cols, always zero
                    } else if (jj >= 683) {
                        if (t < 15) outb[(size_t)(p + 1024) * 1408 + jj] = f2bf(glu); // time shift
                        if (t == 0) outb[(size_t)p * 1408 + jj] = 0;                  // shifted-in zeros
                    } else {
                        outb[(size_t)p * 1408 + jj] = f2bf(glu);
                    }
                }
            }
    } else {
        // EPI 3: finish inline stats, then channel-LN apply + residual + transposed fp32 store
        if (wc == 0) {
#pragma unroll
            for (int m = 0; m < 4; ++m) {
                float s = sst[m], q = sq[m];
                s += __shfl_xor(s, 16); q += __shfl_xor(q, 16);
                s += __shfl_xor(s, 32); q += __shfl_xor(q, 32);
                if ((lane >> 4) == 0) {
                    int row = wr * 64 + m * 16 + (lane & 15);
                    smr[row] = s; smr[128 + row] = q;
                }
            }
        }
        __syncthreads();
        if (tid < 128) {
            float mm = smr[tid] * (1.f / 1365.f);
            float var = smr[128 + tid] * (1.f / 1365.f) - mm * mm;
            smr[tid] = mm;
            smr[128 + tid] = rsqrtf(fmaxf(var, 1e-5f));
        }
        float* ldsT = (float*)lds;
        const int bb = p0 >> 14, tt = (p0 >> 10) & 15, hwb = p0 & 1023;
        float* outp = outf + (size_t)bb * 8388608 + (size_t)tt * 1024 + hwb;
        for (int cg4 = 0; cg4 < 4; ++cg4) {
            __syncthreads();
            if (wc == (cg4 >> 1)) {
#pragma unroll
                for (int m = 0; m < 4; ++m)
#pragma unroll
                    for (int nn = 0; nn < 2; ++nn) {
                        int n = ((cg4 & 1) << 1) + nn;
                        int cl2 = (nn << 4) + (lane & 15);
                        int col = n0 + wc * 64 + n * 16 + (lane & 15);
                        int rl = wr * 64 + m * 16 + ((lane >> 4) << 2);
                        float ssv = ssum[col];
#pragma unroll
                        for (int r = 0; r < 4; ++r) {
                            int p = p0 + rl + r;
                            float vv = smr[128 + rl + r] * (acc[m][n][r] - smr[rl + r] * ssv)
                                     + bf2f(addb[(size_t)p * 512 + col]);
                            ldsT[cl2 * 132 + rl + r] = vv;
                        }
                    }
            }
            __syncthreads();
#pragma unroll
            for (int e = 0; e < 16; ++e) {
                int li = e * 256 + tid;
                int cl2 = li >> 7, hwl = li & 127;
                outp[(size_t)(n0 + cg4 * 32 + cl2) * 16384 + hwl] = ldsT[cl2 * 132 + hwl];
            }
        }
    }
}

// ---------------- attention: per (8-pixel chunk, head) block; 2 blocks/CU ----------------
__global__ __launch_bounds__(256, 2) void attn_kernel(
    const u16* __restrict__ qkv, const float* __restrict__ bias, u16* __restrict__ o)
{
    __shared__ u16 qkvt[3 * 128 * 64];
    __shared__ float pl[128 * 17];
    __shared__ float bl[256];
    const int tid = threadIdx.x, lane = tid & 63, w = tid >> 6;
    const int pc = blockIdx.x, h = blockIdx.y;
    const int b = pc >> 7, hw0 = (pc & 127) << 3;
    bl[tid] = bias[h * 256 + tid];
    for (int i = 0; i < 12; ++i) {
        int idx = w * 12 + i;
        int s = idx >> 4, rb = idx & 15;
        int r = (rb << 3) + (lane >> 3);
        int cg = (lane & 7) ^ (r & 7);
        size_t grow = (size_t)b * 16384 + (size_t)(r >> 3) * 1024 + hw0 + (r & 7);
        gload16(qkv + grow * 1536 + s * 512 + h * 64 + cg * 8, qkvt + s * 8192 + rb * 512);
    }
    __syncthreads();
    {
        const int qrow = tid & 127, hh = tid >> 7;
        const int pix = qrow & 7, ti = qrow >> 3;
        float qv[64];
        const u16* qr = qkvt + qrow * 64;
#pragma unroll
        for (int cc = 0; cc < 8; ++cc) {
            short8 qq = *(const short8*)(qr + ((cc ^ (qrow & 7)) << 3));
#pragma unroll
            for (int j = 0; j < 8; ++j) qv[cc * 8 + j] = bf2f((u16)qq[j]);
        }
#pragma unroll
        for (int tj8 = 0; tj8 < 8; ++tj8) {
            int tj = (hh << 3) + tj8;
            int rk = (tj << 3) + pix;
            const u16* kr = qkvt + 8192 + rk * 64;
            float a = 0.f;
#pragma unroll
            for (int cc = 0; cc < 8; ++cc) {
                short8 kk = *(const short8*)(kr + ((cc ^ (rk & 7)) << 3));
#pragma unroll
                for (int j = 0; j < 8; ++j) a += qv[cc * 8 + j] * bf2f((u16)kk[j]);
            }
            pl[qrow * 17 + tj] = a * 0.125f + bl[(ti << 4) + tj];
        }
    }
    __syncthreads();
    if (tid < 128) {
        float sc[16];
#pragma unroll
        for (int j = 0; j < 16; ++j) sc[j] = pl[tid * 17 + j];
        float mx = sc[0];
#pragma unroll
        for (int j = 1; j < 16; ++j) mx = fmaxf(mx, sc[j]);
        float sum = 0.f;
#pragma unroll
        for (int j = 0; j < 16; ++j) { sc[j] = __expf(sc[j] - mx); sum += sc[j]; }
        float inv = 1.f / sum;
#pragma unroll
        for (int j = 0; j < 16; ++j) pl[tid * 17 + j] = sc[j] * inv;
    }
    __syncthreads();
    {
        const int pix = tid >> 5, dg = tid & 31;
        float v0[16], v1[16];
#pragma unroll
        for (int tj = 0; tj < 16; ++tj) {
            int rv = (tj << 3) + pix;
            unsigned int d = *(const unsigned int*)(qkvt + 16384 + rv * 64 +
                               (((dg >> 2) ^ (rv & 7)) << 3) + ((dg & 3) << 1));
            v0[tj] = bf2f((u16)(d & 0xffff));
            v1[tj] = bf2f((u16)(d >> 16));
        }
#pragma unroll
        for (int ti = 0; ti < 16; ++ti) {
            float a0 = 0.f, a1 = 0.f;
            const float* pr = pl + ((ti << 3) + pix) * 17;
#pragma unroll
            for (int tj = 0; tj < 16; ++tj) {
                float pv = pr[tj];
                a0 += pv * v0[tj];
                a1 += pv * v1[tj];
            }
            size_t p = (size_t)b * 16384 + (size_t)ti * 1024 + hw0 + pix;
            unsigned int pk = (unsigned int)f2bf(a0) | ((unsigned int)f2bf(a1) << 16);
            *(unsigned int*)(o + p * 512 + h * 64 + (dg << 1)) = pk;
        }
    }
}

extern "C" void kernel_launch(void* const* d_in, const int* in_sizes, int n_in,
                              void* d_out, int out_size, void* d_ws, size_t ws_size,
                              hipStream_t stream)
{
    const float* x       = (const float*)d_in[0];
    const int*   frp     = (const int*)d_in[1];
    const float* g_norm  = (const float*)d_in[2];
    const float* Wq      = (const float*)d_in[3];
    const float* Wkv     = (const float*)d_in[4];
    const float* Wo      = (const float*)d_in[5];
    const float* pos_emb = (const float*)d_in[6];
    const float* fr_emb  = (const float*)d_in[7];
    const float* w1      = (const float*)d_in[8];
    const float* b1      = (const float*)d_in[9];
    const float* w2      = (const float*)d_in[10];
    const float* b2      = (const float*)d_in[11];
    const float* w3      = (const float*)d_in[12];
    const float* b3      = (const float*)d_in[13];
    const float* Win     = (const float*)d_in[14];
    const float* chan_g  = (const float*)d_in[15];
    const float* Wout    = (const float*)d_in[16];

    char* ws = (char*)d_ws;
    u16*   wqkvt = (u16*)(ws + 0);
    u16*   wot   = (u16*)(ws + 1572864);
    u16*   winp  = (u16*)(ws + 2097152);
    u16*   woutt = (u16*)(ws + 4980736);
    float* ssum  = (float*)(ws + 6422528);
    float* biasb = (float*)(ws + 6424576);
    u16*   qkv   = (u16*)(ws + 8388608);     // reused as yg after attention
    u16*   xn    = (u16*)(ws + 109051904);   // reused as o_att after qkv GEMM
    u16*   xt    = (u16*)(ws + 142606336);
    u16*   x2    = (u16*)(ws + 176160768);
    u16*   o_att = xn;
    u16*   yg    = qkv;

    prologue_all<<<3216, 256, 0, stream>>>(
        x, frp, g_norm, pos_emb, fr_emb,
        Wq, Wkv, Wo, Win, Wout, chan_g, w1, b1, w2, b2, w3, b3,
        xn, xt, wqkvt, wot, winp, woutt, ssum, biasb);
    gemm_bt<0><<<256 * 12, 256, 0, stream>>>(xn, wqkvt, 512, 12, qkv, nullptr, nullptr,
                                             nullptr, 1536);
    attn_kernel<<<dim3(256, 8), 256, 0, stream>>>(qkv, biasb, o_att);
    gemm_bt<1><<<256 * 4, 256, 0, stream>>>(o_att, wot, 512, 4, x2, nullptr, xt,
                                            nullptr, 512);
    gemm_bt<2><<<256 * 22, 256, 0, stream>>>(x2, winp, 512, 22, yg, nullptr, nullptr,
                                             nullptr, 1408);
    gemm_bt<3><<<256 * 4, 256, 0, stream>>>(yg, woutt, 1408, 4, nullptr, (float*)d_out, x2,
                                            ssum, 512);
}

// Round 12
// 390.024 us; speedup vs baseline: 1.1889x; 1.0289x over previous
//
#include <hip/hip_runtime.h>

using u16 = unsigned short;
using f32x4 = __attribute__((ext_vector_type(4))) float;
using short8 = __attribute__((ext_vector_type(8))) short;

__device__ __forceinline__ float bf2f(u16 u) {
    union { unsigned int i; float f; } v; v.i = ((unsigned int)u) << 16; return v.f;
}
__device__ __forceinline__ u16 f2bf(float f) {
    union { float f; unsigned int i; } v; v.f = f;
    unsigned int u = v.i;
    u += 0x7fffu + ((u >> 16) & 1u);
    return (u16)(u >> 16);
}
__device__ __forceinline__ void gload16(const u16* g, u16* l) {
    __builtin_amdgcn_global_load_lds((const __attribute__((address_space(1))) void*)g,
                                     (__attribute__((address_space(3))) void*)l, 16, 0, 0);
}

// ---------------- fused prologue ----------------
// blocks [0,2048): k1 temporal-LN (vectorized uint2 stores)
// [2048,2240): wqkvt transpose (HEAD-BLOCKED rows: n = h*192 + s*64 + d)
// [2240,2304): wot  [2304,2656): winp  [2656,2832): woutt
// [2832,2960): ssum   [2960,3216): bias MLP
__global__ __launch_bounds__(256) void prologue_all(
    const float* __restrict__ x, const int* __restrict__ frp,
    const float* __restrict__ g_norm, const float* __restrict__ pos_emb,
    const float* __restrict__ fr_emb,
    const float* __restrict__ Wq, const float* __restrict__ Wkv,
    const float* __restrict__ Wo, const float* __restrict__ Win,
    const float* __restrict__ Wout, const float* __restrict__ cg,
    const float* __restrict__ w1, const float* __restrict__ b1,
    const float* __restrict__ w2, const float* __restrict__ b2,
    const float* __restrict__ w3, const float* __restrict__ b3,
    u16* __restrict__ xn, u16* __restrict__ xt,
    u16* __restrict__ wqkvt, u16* __restrict__ wot,
    u16* __restrict__ winp, u16* __restrict__ woutt,
    float* __restrict__ ssum, float* __restrict__ bias)
{
    __shared__ __align__(16) char smem[256 * 36 * 2];
    const int bid = blockIdx.x;
    const int tid = threadIdx.x;
    if (bid < 2048) {
        u16* tile = (u16*)smem;                          // [256][36]
        const int b = bid >> 10, rem = bid & 1023;
        const int hw0 = (rem >> 4) << 4;
        const int c0 = (rem & 15) << 5;
        const int hwl = tid & 15, cl = tid >> 4;
        const int fr = frp[0] - 1;
        float v[2][16], mean2[2], ri2[2], gg2[2], fv2[2];
        for (int cp = 0; cp < 2; ++cp) {
            const int c = c0 + cl + (cp << 4);
            const float* xp = x + (size_t)(b * 512 + c) * 16384 + hw0 + hwl;
            const float fv = fr_emb[fr * 512 + c];
            float s1 = 0.f, s2 = 0.f;
#pragma unroll
            for (int t = 0; t < 16; ++t) {
                float xv = xp[t * 1024];
                v[cp][t] = xv;
                float xe = xv + pos_emb[t * 512 + c] + fv;
                s1 += xe; s2 += xe * xe;
            }
            float m = s1 * 0.0625f;
            float var = s2 * 0.0625f - m * m;
            mean2[cp] = m; ri2[cp] = rsqrtf(fmaxf(var, 1e-5f));
            gg2[cp] = g_norm[c]; fv2[cp] = fv;
        }
        for (int cp = 0; cp < 2; ++cp) {
            const int c = c0 + cl + (cp << 4);
#pragma unroll
            for (int t = 0; t < 16; ++t) {
                float xe = v[cp][t] + pos_emb[t * 512 + c] + fv2[cp];
                tile[((t << 4) + hwl) * 36 + cl + (cp << 4)] = f2bf((xe - mean2[cp]) * ri2[cp] * gg2[cp]);
            }
        }
        __syncthreads();
        for (int it = 0; it < 8; ++it) {
            int idx = it * 256 + tid;
            int rowl = idx >> 3, c4 = (idx & 7) << 2;
            size_t p = (size_t)b * 16384 + (size_t)(rowl >> 4) * 1024 + hw0 + (rowl & 15);
            uint2 d = *(const uint2*)(tile + rowl * 36 + c4);
            *(uint2*)(xn + p * 512 + c0 + c4) = d;
        }
        __syncthreads();
        for (int cp = 0; cp < 2; ++cp)
#pragma unroll
            for (int t = 0; t < 16; ++t)
                tile[((t << 4) + hwl) * 36 + cl + (cp << 4)] = f2bf(v[cp][t]);
        __syncthreads();
        for (int it = 0; it < 8; ++it) {
            int idx = it * 256 + tid;
            int rowl = idx >> 3, c4 = (idx & 7) << 2;
            size_t p = (size_t)b * 16384 + (size_t)(rowl >> 4) * 1024 + hw0 + (rowl & 15);
            uint2 d = *(const uint2*)(tile + rowl * 36 + c4);
            *(uint2*)(xt + p * 512 + c0 + c4) = d;
        }
        return;
    }
    if (bid < 2832) {
        float* tf = (float*)smem;                        // [64][65]
        int r0, c0, ldout;
        u16* dst;
        int kind;
        int tt;
        if (bid < 2240)      { tt = bid - 2048; r0 = (tt >> 3) << 6; c0 = (tt & 7) << 6;  dst = wqkvt; ldout = 512;  kind = 0; }
        else if (bid < 2304) { tt = bid - 2240; r0 = (tt >> 3) << 6; c0 = (tt & 7) << 6;  dst = wot;   ldout = 512;  kind = 1; }
        else if (bid < 2656) { tt = bid - 2304; r0 = (tt >> 3) << 6; c0 = (tt & 7) << 6;  dst = winp;  ldout = 512;  kind = 2; }
        else                 { tt = bid - 2656; r0 = (tt / 22) << 6; c0 = (tt % 22) << 6; dst = woutt; ldout = 1408; kind = 3; }
#pragma unroll 1
        for (int i = 0; i < 16; ++i) {
            int idx = tid + (i << 8);
            int cl = idx >> 6, rl = idx & 63;
            int r = r0 + rl, c = c0 + cl;
            float v;
            if (kind == 0) {
                // head-blocked row: r = h*192 + s*64 + d
                int h = r / 192, wch = r - h * 192;
                int s = wch >> 6, d = wch & 63;
                int oc = h * 64 + d;
                v = (s == 0) ? Wq[c * 512 + oc]
                             : Wkv[c * 1024 + (s - 1) * 512 + oc];
            } else if (kind == 1) {
                v = Wo[c * 512 + r];
            } else if (kind == 2) {
                int jj = ((r >> 5) << 4) + (r & 15);
                int gate = (r >> 4) & 1;
                v = (jj < 1365) ? Win[c * 2730 + jj + gate * 1365] : 0.f;
            } else {
                v = (c < 1365) ? Wout[c * 512 + r] * cg[c] : 0.f;
            }
            tf[rl * 65 + cl] = v;
        }
        __syncthreads();
        for (int i = 0; i < 4; ++i) {
            int idx = tid + (i << 8);
            int rl = idx >> 4, c4 = (idx & 15) << 2;
            const float* tp = tf + rl * 65 + c4;
            unsigned int lo = ((unsigned int)f2bf(tp[1]) << 16) | f2bf(tp[0]);
            unsigned int hi = ((unsigned int)f2bf(tp[3]) << 16) | f2bf(tp[2]);
            *(uint2*)(dst + (size_t)(r0 + rl) * ldout + c0 + c4) = make_uint2(lo, hi);
        }
        return;
    }
    if (bid < 2960) {
        int c = ((bid - 2832) << 2) + (tid >> 6);
        int lane = tid & 63;
        float s = 0.f;
        for (int j = lane; j < 1365; j += 64) s += Wout[j * 512 + c] * cg[j];
        for (int off = 32; off; off >>= 1) s += __shfl_xor(s, off);
        if (lane == 0) ssum[c] = s;
        return;
    }
    {
        float* h1 = (float*)smem;
        float* h2 = h1 + 256;
        int rc = bid - 2960;
        int ti = rc >> 4, tj = rc & 15;
        int j = tid;
        float r = (float)(ti - tj);
        float rl = (r > 0.f) ? logf(r + 1.f) : ((r < 0.f) ? -logf(1.f - r) : 0.f);
        float a = rl * w1[j] + b1[j];
        h1[j] = a / (1.f + __expf(-a));
        __syncthreads();
        float acc = b2[j];
        for (int k = 0; k < 256; ++k) acc += h1[k] * w2[k * 256 + j];
        h2[j] = acc / (1.f + __expf(-acc));
        __syncthreads();
        if (j < 8) {
            float ab = b3[j];
            for (int k = 0; k < 256; ++k) ab += h2[k] * w3[k * 8 + j];
            bias[j * 256 + ti * 16 + tj] = ab;
        }
    }
}

// ======== fused QKV GEMM + attention: block = (8 pixels x 16 t) x (head h: q,k,v) ========
// A rows gathered per-row: tile row r -> p = b*16384 + (r>>3)*1024 + hw0 + (r&7).
// B head-blocked [h][s*64+d][512]. Tile 128x192, 4 waves (2M x 2N of 96), K=512.
// Epilogue: scatter acc -> LDS qkvt (attn layout, XOR swizzle), then QK^T/softmax/PV, write o.
__global__ __launch_bounds__(256, 2) void gemm_qkv_attn(
    const u16* __restrict__ A, const u16* __restrict__ B,
    const float* __restrict__ bias, u16* __restrict__ o)
{
    __shared__ __align__(16) char smem[58880];
    u16* lA = (u16*)smem;                  // staging A [128][64]  (16 KB)
    u16* lB = (u16*)(smem + 16384);        // staging B [192][64]  (24 KB)
    u16* qkvt = (u16*)smem;                // after K-loop: [3][128][64] (48 KB, overlaps staging)
    float* pl = (float*)(smem + 49152);    // [128][17]
    float* bl = (float*)(smem + 57856);    // [256]
    const int tid = threadIdx.x, lane = tid & 63, w = tid >> 6;
    const int wr = w >> 1, wc = w & 1;
    const int l15 = lane & 15, l16 = lane >> 4;
    const int bidf = ((blockIdx.x & 7) << 8) + (blockIdx.x >> 3);   // XCD-chunked
    const int hwc = bidf >> 3, h = bidf & 7;                         // head-fastest
    const int b = hwc >> 7, hw0 = (hwc & 127) << 3;
    const u16* Bg = B + (size_t)h * 192 * 512;

    bl[tid] = bias[h * 256 + tid];

    f32x4 acc[4][6] = {};
    for (int kt = 0; kt < 512; kt += 64) {
        for (int i = 0; i < 4; ++i) {
            int rb = w * 4 + i;
            int r = rb * 8 + (lane >> 3);
            int cg = (lane & 7) ^ (r & 7);
            size_t p = (size_t)b * 16384 + (size_t)(r >> 3) * 1024 + hw0 + (r & 7);
            gload16(A + p * 512 + kt + cg * 8, lA + rb * 512);
        }
        for (int i = 0; i < 6; ++i) {
            int rb = w * 6 + i;
            int r = rb * 8 + (lane >> 3);
            int cg = (lane & 7) ^ (r & 7);
            gload16(Bg + (size_t)r * 512 + kt + cg * 8, lB + rb * 512);
        }
        __syncthreads();
#pragma unroll
        for (int kk = 0; kk < 2; ++kk) {
            short8 av[4], bv[6];
#pragma unroll
            for (int m = 0; m < 4; ++m) {
                int r = wr * 64 + m * 16 + l15;
                int cc = ((kk << 2) + l16) ^ (r & 7);
                av[m] = *(const short8*)(lA + r * 64 + cc * 8);
            }
#pragma unroll
            for (int n = 0; n < 6; ++n) {
                int r = wc * 96 + n * 16 + l15;
                int cc = ((kk << 2) + l16) ^ (r & 7);
                bv[n] = *(const short8*)(lB + r * 64 + cc * 8);
            }
#pragma unroll
            for (int m = 0; m < 4; ++m)
#pragma unroll
                for (int n = 0; n < 6; ++n)
                    acc[m][n] = __builtin_amdgcn_mfma_f32_16x16x32_bf16(av[m], bv[n], acc[m][n], 0, 0, 0);
        }
        __syncthreads();
    }

    // scatter acc -> qkvt bf16 (attn layout with XOR-swizzled 8-col chunks)
#pragma unroll
    for (int m = 0; m < 4; ++m)
#pragma unroll
        for (int n = 0; n < 6; ++n) {
            int rl = wr * 64 + m * 16 + (l16 << 2);
            int nc = wc * 96 + n * 16 + l15;
            int s = nc >> 6, d = nc & 63;
#pragma unroll
            for (int r = 0; r < 4; ++r) {
                int row = rl + r;
                qkvt[s * 8192 + row * 64 + ((((d >> 3) ^ (row & 7))) << 3) + (d & 7)] =
                    f2bf(acc[m][n][r]);
            }
        }
    __syncthreads();

    // QK^T + bias
    {
        const int qrow = tid & 127, hh = tid >> 7;
        const int pix = qrow & 7, ti = qrow >> 3;
        float qv[64];
        const u16* qr = qkvt + qrow * 64;
#pragma unroll
        for (int cc = 0; cc < 8; ++cc) {
            short8 qq = *(const short8*)(qr + ((cc ^ (qrow & 7)) << 3));
#pragma unroll
            for (int j = 0; j < 8; ++j) qv[cc * 8 + j] = bf2f((u16)qq[j]);
        }
#pragma unroll
        for (int tj8 = 0; tj8 < 8; ++tj8) {
            int tj = (hh << 3) + tj8;
            int rk = (tj << 3) + pix;
            const u16* kr = qkvt + 8192 + rk * 64;
            float a = 0.f;
#pragma unroll
            for (int cc = 0; cc < 8; ++cc) {
                short8 kk = *(const short8*)(kr + ((cc ^ (rk & 7)) << 3));
#pragma unroll
                for (int j = 0; j < 8; ++j) a += qv[cc * 8 + j] * bf2f((u16)kk[j]);
            }
            pl[qrow * 17 + tj] = a * 0.125f + bl[(ti << 4) + tj];
        }
    }
    __syncthreads();
    if (tid < 128) {
        float sc[16];
#pragma unroll
        for (int j = 0; j < 16; ++j) sc[j] = pl[tid * 17 + j];
        float mx = sc[0];
#pragma unroll
        for (int j = 1; j < 16; ++j) mx = fmaxf(mx, sc[j]);
        float sum = 0.f;
#pragma unroll
        for (int j = 0; j < 16; ++j) { sc[j] = __expf(sc[j] - mx); sum += sc[j]; }
        float inv = 1.f / sum;
#pragma unroll
        for (int j = 0; j < 16; ++j) pl[tid * 17 + j] = sc[j] * inv;
    }
    __syncthreads();
    // PV + direct global store
    {
        const int pix = tid >> 5, dg = tid & 31;
        float v0[16], v1[16];
#pragma unroll
        for (int tj = 0; tj < 16; ++tj) {
            int rv = (tj << 3) + pix;
            unsigned int d = *(const unsigned int*)(qkvt + 16384 + rv * 64 +
                               (((dg >> 2) ^ (rv & 7)) << 3) + ((dg & 3) << 1));
            v0[tj] = bf2f((u16)(d & 0xffff));
            v1[tj] = bf2f((u16)(d >> 16));
        }
#pragma unroll
        for (int ti = 0; ti < 16; ++ti) {
            float a0 = 0.f, a1 = 0.f;
            const float* pr = pl + ((ti << 3) + pix) * 17;
#pragma unroll
            for (int tj = 0; tj < 16; ++tj) {
                float pv = pr[tj];
                a0 += pv * v0[tj];
                a1 += pv * v1[tj];
            }
            size_t p = (size_t)b * 16384 + (size_t)ti * 1024 + hw0 + pix;
            unsigned int pk = (unsigned int)f2bf(a0) | ((unsigned int)f2bf(a1) << 16);
            *(unsigned int*)(o + p * 512 + h * 64 + (dg << 1)) = pk;
        }
    }
}

// ---------------- generic MFMA GEMM: C[M=32768][N] = A[M][K] * B^T[N][K] ----------------
// 128x128 tile, 256 thr, single-buffer 2-barrier (proven structure) + XCD-chunked swizzle.
// EPI 1: +residual -> bf16 (x2). EPI 2: GLU + time-shifted store.
// EPI 3: inline channel-LN stats + LN apply + residual + fp32 transpose store.
template<int EPI>
__global__ __launch_bounds__(256, 2) void gemm_bt(
    const u16* __restrict__ A, const u16* __restrict__ B, int K, int Nb,
    u16* __restrict__ outb, float* __restrict__ outf,
    const u16* __restrict__ addb,
    const float* __restrict__ ssum, int ldOut)
{
    __shared__ u16 lds[2 * 128 * 64];
    __shared__ float smr[256];          // EPI3: [0:128) mean, [128:256) rinv
    u16* lA = lds;
    u16* lB = lds + 128 * 64;
    const int tid = threadIdx.x, lane = tid & 63, w = tid >> 6;
    const int wr = w >> 1, wc = w & 1;
    const int cpx = gridDim.x >> 3;
    const int wgid = (blockIdx.x & 7) * cpx + (blockIdx.x >> 3);
    const int p0 = (wgid / Nb) * 128, n0 = (wgid % Nb) * 128;
    f32x4 acc[4][4] = {};
    float sst[4] = {}, sq[4] = {};
    for (int kt = 0; kt < K; kt += 64) {
        for (int i = 0; i < 4; ++i) {
            int rb = w * 4 + i;
            int r = rb * 8 + (lane >> 3);
            int cg = (lane & 7) ^ (r & 7);
            gload16(A + (size_t)(p0 + r) * K + (kt + cg * 8), lA + rb * 512);
            gload16(B + (size_t)(n0 + r) * K + (kt + cg * 8), lB + rb * 512);
        }
        __syncthreads();
#pragma unroll
        for (int kk = 0; kk < 2; ++kk) {
            short8 av[4], bv[4];
#pragma unroll
            for (int m = 0; m < 4; ++m) {
                int r = wr * 64 + m * 16 + (lane & 15);
                int cc = ((kk << 2) + (lane >> 4)) ^ (r & 7);
                av[m] = *(const short8*)(lA + r * 64 + cc * 8);
            }
#pragma unroll
            for (int n = 0; n < 4; ++n) {
                int r = wc * 64 + n * 16 + (lane & 15);
                int cc = ((kk << 2) + (lane >> 4)) ^ (r & 7);
                bv[n] = *(const short8*)(lB + r * 64 + cc * 8);
            }
            if constexpr (EPI == 3) {
                if (wc == 0) {
#pragma unroll
                    for (int m = 0; m < 4; ++m)
#pragma unroll
                        for (int j = 0; j < 8; ++j) {
                            float v = bf2f((u16)av[m][j]);
                            sst[m] += v; sq[m] += v * v;
                        }
                }
            }
#pragma unroll
            for (int m = 0; m < 4; ++m)
#pragma unroll
                for (int n = 0; n < 4; ++n)
                    acc[m][n] = __builtin_amdgcn_mfma_f32_16x16x32_bf16(av[m], bv[n], acc[m][n], 0, 0, 0);
        }
        __syncthreads();
    }

    if constexpr (EPI == 1) {
#pragma unroll
        for (int m = 0; m < 4; ++m)
#pragma unroll
            for (int n = 0; n < 4; ++n) {
                int row = p0 + wr * 64 + m * 16 + ((lane >> 4) << 2);
                int col = n0 + wc * 64 + n * 16 + (lane & 15);
#pragma unroll
                for (int r = 0; r < 4; ++r) {
                    float vv = acc[m][n][r] + bf2f(addb[(size_t)(row + r) * ldOut + col]);
                    outb[(size_t)(row + r) * ldOut + col] = f2bf(vv);
                }
            }
    } else if constexpr (EPI == 2) {
#pragma unroll
        for (int m = 0; m < 4; ++m)
#pragma unroll
            for (int np = 0; np < 2; ++np) {
                int nv = np << 1;
                int colBase = n0 + wc * 64 + nv * 16 + (lane & 15);
                int jj = ((colBase >> 5) << 4) + (colBase & 15);
                int rowb = p0 + wr * 64 + m * 16 + ((lane >> 4) << 2);
                int t = (rowb >> 10) & 15;
#pragma unroll
                for (int r = 0; r < 4; ++r) {
                    int p = rowb + r;
                    float vv = acc[m][nv][r], gv = acc[m][nv + 1][r];
                    float glu = vv * 0.5f * gv * (1.f + erff(gv * 0.70710678f));
                    if (jj >= 1365) {
                        outb[(size_t)p * 1408 + jj] = 0;
                    } else if (jj >= 683) {
                        if (t < 15) outb[(size_t)(p + 1024) * 1408 + jj] = f2bf(glu);
                        if (t == 0) outb[(size_t)p * 1408 + jj] = 0;
                    } else {
                        outb[(size_t)p * 1408 + jj] = f2bf(glu);
                    }
                }
            }
    } else {
        // EPI 3
        if (wc == 0) {
#pragma unroll
            for (int m = 0; m < 4; ++m) {
                float s = sst[m], q = sq[m];
                s += __shfl_xor(s, 16); q += __shfl_xor(q, 16);
                s += __shfl_xor(s, 32); q += __shfl_xor(q, 32);
                if ((lane >> 4) == 0) {
                    int row = wr * 64 + m * 16 + (lane & 15);
                    smr[row] = s; smr[128 + row] = q;
                }
            }
        }
        __syncthreads();
        if (tid < 128) {
            float mm = smr[tid] * (1.f / 1365.f);
            float var = smr[128 + tid] * (1.f / 1365.f) - mm * mm;
            smr[tid] = mm;
            smr[128 + tid] = rsqrtf(fmaxf(var, 1e-5f));
        }
        float* ldsT = (float*)lds;
        const int bb = p0 >> 14, tt = (p0 >> 10) & 15, hwb = p0 & 1023;
        float* outp = outf + (size_t)bb * 8388608 + (size_t)tt * 1024 + hwb;
        for (int cg4 = 0; cg4 < 4; ++cg4) {
            __syncthreads();
            if (wc == (cg4 >> 1)) {
#pragma unroll
                for (int m = 0; m < 4; ++m)
#pragma unroll
                    for (int nn = 0; nn < 2; ++nn) {
                        int n = ((cg4 & 1) << 1) + nn;
                        int cl2 = (nn << 4) + (lane & 15);
                        int col = n0 + wc * 64 + n * 16 + (lane & 15);
                        int rl = wr * 64 + m * 16 + ((lane >> 4) << 2);
                        float ssv = ssum[col];
#pragma unroll
                        for (int r = 0; r < 4; ++r) {
                            int p = p0 + rl + r;
                            float vv = smr[128 + rl + r] * (acc[m][n][r] - smr[rl + r] * ssv)
                                     + bf2f(addb[(size_t)p * 512 + col]);
                            ldsT[cl2 * 132 + rl + r] = vv;
                        }
                    }
            }
            __syncthreads();
#pragma unroll
            for (int e = 0; e < 16; ++e) {
                int li = e * 256 + tid;
                int cl2 = li >> 7, hwl = li & 127;
                outp[(size_t)(n0 + cg4 * 32 + cl2) * 16384 + hwl] = ldsT[cl2 * 132 + hwl];
            }
        }
    }
}

extern "C" void kernel_launch(void* const* d_in, const int* in_sizes, int n_in,
                              void* d_out, int out_size, void* d_ws, size_t ws_size,
                              hipStream_t stream)
{
    const float* x       = (const float*)d_in[0];
    const int*   frp     = (const int*)d_in[1];
    const float* g_norm  = (const float*)d_in[2];
    const float* Wq      = (const float*)d_in[3];
    const float* Wkv     = (const float*)d_in[4];
    const float* Wo      = (const float*)d_in[5];
    const float* pos_emb = (const float*)d_in[6];
    const float* fr_emb  = (const float*)d_in[7];
    const float* w1      = (const float*)d_in[8];
    const float* b1      = (const float*)d_in[9];
    const float* w2      = (const float*)d_in[10];
    const float* b2      = (const float*)d_in[11];
    const float* w3      = (const float*)d_in[12];
    const float* b3      = (const float*)d_in[13];
    const float* Win     = (const float*)d_in[14];
    const float* chan_g  = (const float*)d_in[15];
    const float* Wout    = (const float*)d_in[16];

    char* ws = (char*)d_ws;
    u16*   wqkvt = (u16*)(ws + 0);
    u16*   wot   = (u16*)(ws + 1572864);
    u16*   winp  = (u16*)(ws + 2097152);
    u16*   woutt = (u16*)(ws + 4980736);
    float* ssum  = (float*)(ws + 6422528);
    float* biasb = (float*)(ws + 6424576);
    u16*   big   = (u16*)(ws + 8388608);     // o_att, then reused as yg
    u16*   xn    = (u16*)(ws + 109051904);
    u16*   xt    = (u16*)(ws + 142606336);
    u16*   x2    = (u16*)(ws + 176160768);
    u16*   o_att = big;
    u16*   yg    = big;

    prologue_all<<<3216, 256, 0, stream>>>(
        x, frp, g_norm, pos_emb, fr_emb,
        Wq, Wkv, Wo, Win, Wout, chan_g, w1, b1, w2, b2, w3, b3,
        xn, xt, wqkvt, wot, winp, woutt, ssum, biasb);
    gemm_qkv_attn<<<2048, 256, 0, stream>>>(xn, wqkvt, biasb, o_att);
    gemm_bt<1><<<256 * 4, 256, 0, stream>>>(o_att, wot, 512, 4, x2, nullptr, xt,
                                            nullptr, 512);
    gemm_bt<2><<<256 * 22, 256, 0, stream>>>(x2, winp, 512, 22, yg, nullptr, nullptr,
                                             nullptr, 1408);
    gemm_bt<3><<<256 * 4, 256, 0, stream>>>(yg, woutt, 1408, 4, nullptr, (float*)d_out, x2,
                                            ssum, 512);
}